// Round 5
// baseline (2230.431 us; speedup 1.0000x reference)
//
#include <hip/hip_runtime.h>
#include <math.h>

// CausalVisionMamba — round 5: transposed B/C for scan, fused transpose-cvt
// staging in MFMA GEMMs (no k_tcvt), CH=28, vectorized conv.

namespace {
constexpr int NB = 4;
constexpr int SL = 3136;
constexpr int DM = 384;
constexpr int DI = 768;
constexpr int DSN = 16;
constexpr int DR = 24;
constexpr int NLAYER = 4;
constexpr int NCLS = 1000;
constexpr int XPN = DR + 2 * DSN;  // 56
constexpr int CH = 28;
constexpr int CLEN = SL / CH;      // 112
constexpr int NCHAIN = NB * DI;    // 3072
constexpr int NG = NCHAIN * CH;    // 86016
}

typedef float f32x4 __attribute__((ext_vector_type(4)));
typedef short short8 __attribute__((ext_vector_type(8)));
typedef short short4v __attribute__((ext_vector_type(4)));

__device__ __forceinline__ float siluf(float x) { return x / (1.f + expf(-x)); }
__device__ __forceinline__ float softplusf(float x) {
  return fmaxf(x, 0.f) + log1pf(expf(-fabsf(x)));
}
__device__ __forceinline__ unsigned short cvt_bf(float f) {
  unsigned int x = __float_as_uint(f);
  unsigned int r = (x + 0x7fffu + ((x >> 16) & 1u)) >> 16;  // RNE
  return (unsigned short)r;
}

// ---------------- patch embed: t[b][l][dm] fp32 + tb bf16 ----------------
__global__ void k_patch(const float* __restrict__ x, const float* __restrict__ w,
                        const float* __restrict__ bias, float* __restrict__ t,
                        unsigned short* __restrict__ tb) {
  const int blk = blockIdx.x;
  const int b = blk / SL, l = blk % SL;
  const int hh = l / 56, ww = l % 56;
  __shared__ float patch[48];
  const int tid = threadIdx.x;
  if (tid < 48) {
    const int c = tid / 16, kh = (tid % 16) / 4, kw = tid % 4;
    patch[tid] = x[((size_t)(b * 3 + c) * 224 + (hh * 4 + kh)) * 224 + (ww * 4 + kw)];
  }
  __syncthreads();
  for (int dm = tid; dm < DM; dm += 128) {
    const float* wr = w + (size_t)dm * 48;
    float acc = bias[dm];
#pragma unroll
    for (int p = 0; p < 48; ++p) acc = fmaf(patch[p], wr[p], acc);
    const size_t o = ((size_t)b * SL + l) * DM + dm;
    t[o] = acc;
    tb[o] = cvt_bf(acc);
  }
}

// ---------------- bf16 MFMA GEMM: D = A[M,K](bf16) * W[N,K]^T(fp32->bf16) -------
// AT=false: A is bf16 [M][K] row-major.
// AT=true : A is fp32 [B][K][SL]; staged with fused transpose + bf16 cvt.
// MEPI 0: x_proj  -> n<DR: out=dbl24[m][24]; DR<=n<NCAP: out2=BCt[b][n-DR][l]
// MEPI 1: in_proj -> n<DI: out=xcT [b][n][l]; n>=DI: out2=resT [b][n][l]
// MEPI 2: out_proj-> out[m*DM+n] += acc (t) and outb = bf16(new t)
template <int BM, int BN, int MEPI, int NCAP, bool AT>
__global__ __launch_bounds__(256) void k_mgemm(
    const unsigned short* __restrict__ A, const float* __restrict__ Afp,
    const float* __restrict__ W, float* __restrict__ out,
    float* __restrict__ out2, unsigned short* __restrict__ outb, const int K) {
  constexpr int WM = BM / 2, WN = BN / 2, FM = WM / 16, FN = WN / 16;
  constexpr bool NMASK = (NCAP % BN) != 0;
  __shared__ unsigned short As[BM * 40];
  __shared__ unsigned short Bs[BN * 40];
  const int tid = threadIdx.x;
  const int lane = tid & 63, wave = tid >> 6;
  const int wm = wave >> 1, wn = wave & 1;
  const int m0 = blockIdx.x * BM, n0 = blockIdx.y * BN;
  const int r16 = lane & 15, kg = (lane >> 4) * 8;
  f32x4 acc[FM][FN] = {};
  const int nk = K >> 5;
  for (int kt = 0; kt < nk; ++kt) {
    const int k0 = kt << 5;
    if constexpr (AT) {
      // fp32 [B][K][SL] -> bf16 LDS [m][k], fused transpose.
      // lanes: kp fast (16 k-pairs), lq slow -> conflict-free-ish LDS writes,
      // 64B-coalesced global reads.
#pragma unroll
      for (int it = 0; it < BM / 64; ++it) {
        const int c = tid + 256 * it;
        const int kp = c & 15;
        const int lq = (c >> 4) * 4;
        const int mrow = m0 + lq;
        const int bb = mrow / SL;
        const size_t rowo = (size_t)(bb * K + k0 + 2 * kp) * SL + (mrow - bb * SL);
        const float4 v0 = *(const float4*)&Afp[rowo];
        const float4 v1 = *(const float4*)&Afp[rowo + SL];
        const float ve0[4] = {v0.x, v0.y, v0.z, v0.w};
        const float ve1[4] = {v1.x, v1.y, v1.z, v1.w};
#pragma unroll
        for (int e = 0; e < 4; ++e) {
          const unsigned int pk =
              (unsigned int)cvt_bf(ve0[e]) | ((unsigned int)cvt_bf(ve1[e]) << 16);
          *(unsigned int*)&As[(lq + e) * 40 + 2 * kp] = pk;
        }
      }
    } else {
#pragma unroll
      for (int it = 0; it < (BM * 4) / 256; ++it) {
        const int c = tid + 256 * it;
        const int row = c >> 2, ks = (c & 3) * 8;
        *(short8*)&As[row * 40 + ks] =
            *(const short8*)&A[(size_t)(m0 + row) * K + k0 + ks];
      }
    }
    // B staging: fp32 global -> cvt -> LDS
#pragma unroll
    for (int it = 0; it < (BN * 8) / 256; ++it) {
      const int c = tid + 256 * it;
      const int row = c >> 3, ks = (c & 7) * 4;
      float4 v = make_float4(0.f, 0.f, 0.f, 0.f);
      if (!NMASK || (n0 + row) < NCAP)
        v = *(const float4*)&W[(size_t)(n0 + row) * K + k0 + ks];
      short4v o4;
      o4[0] = (short)cvt_bf(v.x);
      o4[1] = (short)cvt_bf(v.y);
      o4[2] = (short)cvt_bf(v.z);
      o4[3] = (short)cvt_bf(v.w);
      *(short4v*)&Bs[row * 40 + ks] = o4;
    }
    __syncthreads();
    short8 af[FM], bfv[FN];
#pragma unroll
    for (int i = 0; i < FM; ++i)
      af[i] = *(const short8*)&As[(wm * WM + i * 16 + r16) * 40 + kg];
#pragma unroll
    for (int j = 0; j < FN; ++j)
      bfv[j] = *(const short8*)&Bs[(wn * WN + j * 16 + r16) * 40 + kg];
#pragma unroll
    for (int i = 0; i < FM; ++i)
#pragma unroll
      for (int j = 0; j < FN; ++j)
        acc[i][j] = __builtin_amdgcn_mfma_f32_16x16x32_bf16(af[i], bfv[j],
                                                            acc[i][j], 0, 0, 0);
    __syncthreads();
  }

  // Epilogue. C/D layout: col n = lane&15, rows m = (lane>>4)*4 + r.
#pragma unroll
  for (int i = 0; i < FM; ++i) {
#pragma unroll
    for (int j = 0; j < FN; ++j) {
      const int n = n0 + wn * WN + j * 16 + r16;
      const int mb = m0 + wm * WM + i * 16 + ((lane >> 4) << 2);
      f32x4 a = acc[i][j];
      if (MEPI == 0) {
        const int bb = mb / SL;
        const int ll = mb - bb * SL;
        if (n < DR) {
#pragma unroll
          for (int r = 0; r < 4; ++r) out[(size_t)(mb + r) * DR + n] = a[r];
        } else if (n < NCAP) {
          *(f32x4*)&out2[((size_t)(bb * 32 + (n - DR))) * SL + ll] = a;
        }
      } else if (MEPI == 1) {
        float* base = out;
        int nn = n;
        if (n >= DI) { base = out2; nn = n - DI; }
        const int bb = mb / SL;
        const int ll = mb - bb * SL;
        *(f32x4*)&base[((size_t)(bb * DI + nn)) * SL + ll] = a;
      } else {  // MEPI 2
#pragma unroll
        for (int r = 0; r < 4; ++r) {
          const size_t off = (size_t)(mb + r) * DM + n;
          const float nv = out[off] + a[r];
          out[off] = nv;
          outb[off] = cvt_bf(nv);
        }
      }
    }
  }
}

// ---------------- fp32 SIMT GEMM (dt_proj, K=24) ----------------
template <int EPI, bool KTAIL, int NCAP>
__global__ __launch_bounds__(256) void k_gemm(
    const float* __restrict__ A, const float* __restrict__ W,
    const float* __restrict__ bias, float* __restrict__ out, int K, int lda) {
  __shared__ float sm[4352];
  const int tid = threadIdx.x;
  const int m0 = blockIdx.x * 64;
  const int n0 = blockIdx.y * 64;
  const int b = m0 / SL, l0 = m0 % SL;
  const int tm = tid >> 4, tn = tid & 15;
  float acc[4][4] = {};
  float* As = sm;
  float* Ws = sm + 16 * 68;

  const int nk = (K + 15) / 16;
  for (int kt = 0; kt < nk; ++kt) {
    const int k0 = kt * 16;
    {
      const int row = tid >> 2;
      const int kq = (tid & 3) * 4;
      const int kb = k0 + kq;
      float4 v = make_float4(0.f, 0.f, 0.f, 0.f);
      if (!KTAIL || kb < K) v = *(const float4*)&A[(size_t)(m0 + row) * lda + kb];
      As[(kq + 0) * 68 + row] = v.x;
      As[(kq + 1) * 68 + row] = v.y;
      As[(kq + 2) * 68 + row] = v.z;
      As[(kq + 3) * 68 + row] = v.w;
    }
    {
      const int row = tid >> 2;
      const int kq = (tid & 3) * 4;
      const int kb = k0 + kq;
      float4 v = make_float4(0.f, 0.f, 0.f, 0.f);
      const bool nok = (NCAP % 64 == 0) || (n0 + row < NCAP);
      if (nok && (!KTAIL || kb < K)) v = *(const float4*)&W[(size_t)(n0 + row) * K + kb];
      Ws[(kq + 0) * 68 + row] = v.x;
      Ws[(kq + 1) * 68 + row] = v.y;
      Ws[(kq + 2) * 68 + row] = v.z;
      Ws[(kq + 3) * 68 + row] = v.w;
    }
    __syncthreads();
#pragma unroll
    for (int kk = 0; kk < 16; ++kk) {
      const float4 av = *(const float4*)&As[kk * 68 + 4 * tm];
      const float4 wv = *(const float4*)&Ws[kk * 68 + 4 * tn];
      const float ax[4] = {av.x, av.y, av.z, av.w};
      const float wx[4] = {wv.x, wv.y, wv.z, wv.w};
#pragma unroll
      for (int i = 0; i < 4; ++i)
#pragma unroll
        for (int j = 0; j < 4; ++j) acc[i][j] = fmaf(ax[i], wx[j], acc[i][j]);
    }
    __syncthreads();
  }

  // transpose epilogue through LDS -> [b][n][l] (EPI==2: softplus+bias)
#pragma unroll
  for (int j = 0; j < 4; ++j) {
    const int nn = 4 * tn + j;
#pragma unroll
    for (int i = 0; i < 4; ++i) {
      float v = acc[i][j];
      if (EPI == 2) v = softplusf(v + bias[n0 + nn]);
      sm[nn * 68 + 4 * tm + i] = v;
    }
  }
  __syncthreads();
  const int row = tid >> 2;
  const int seg = (tid & 3) * 16;
  const float* src = &sm[row * 68 + seg];
  float* dst = out + ((size_t)(b * DI + n0 + row)) * SL + l0 + seg;
#pragma unroll
  for (int q = 0; q < 4; ++q) {
    *(float4*)&dst[q * 4] = *(const float4*)&src[q * 4];
  }
}

// ---------------- depthwise causal conv1d + bias + silu (4 l per thread) --------
__global__ void k_conv(const float* __restrict__ xcT, const float* __restrict__ cw,
                       const float* __restrict__ cb, float* __restrict__ uT) {
  const size_t idx = (size_t)blockIdx.x * 256 + threadIdx.x;
  const int l4 = (int)(idx % (SL / 4)) * 4;
  const int bd = (int)(idx / (SL / 4));
  const int d = bd % DI;
  const float* row = xcT + (size_t)bd * SL;
  const float4 w = *(const float4*)&cw[d * 4];
  const float4 cur = *(const float4*)&row[l4];
  float p1 = 0.f, p2 = 0.f, p3 = 0.f;
  if (l4 > 0) {
    const float4 pv = *(const float4*)&row[l4 - 4];
    p1 = pv.y; p2 = pv.z; p3 = pv.w;
  }
  const float cbd = cb[d];
  float4 o;
  o.x = cbd + w.w * cur.x + w.z * p3 + w.y * p2 + w.x * p1;
  o.y = cbd + w.w * cur.y + w.z * cur.x + w.y * p3 + w.x * p2;
  o.z = cbd + w.w * cur.z + w.z * cur.y + w.y * cur.x + w.x * p3;
  o.w = cbd + w.w * cur.w + w.z * cur.z + w.y * cur.y + w.x * cur.x;
  o.x = siluf(o.x); o.y = siluf(o.y); o.z = siluf(o.z); o.w = siluf(o.w);
  *(float4*)&uT[(size_t)bd * SL + l4] = o;
}

// ---------------- chunked selective scan (BCt layout: [b][32][SL]) --------------
__global__ __launch_bounds__(256) void k_scan1(
    const float* __restrict__ deltaT, const float* __restrict__ uT,
    const float* __restrict__ BCt, const float* __restrict__ A_log,
    float* __restrict__ hend, float* __restrict__ aprod) {
  const int tid = threadIdx.x;
  const int n = tid & 15, g = tid >> 4;
  const int gidx = blockIdx.x * 16 + g;
  const int chain = gidx / CH, c = gidx % CH;
  const int b = chain / DI, d = chain % DI;
  const float a2 = -expf(A_log[d * DSN + n]) * 1.44269504088896341f;
  const int base = c * CLEN;
  const float* drow = deltaT + (size_t)chain * SL + base;
  const float* urow = uT + (size_t)chain * SL + base;
  const float* Brow = BCt + (size_t)(b * 32 + n) * SL + base;
  float h = 0.f, dsum = 0.f;
  for (int l0 = 0; l0 < CLEN; l0 += 8) {
    const float4 dv0 = *(const float4*)&drow[l0];
    const float4 dv1 = *(const float4*)&drow[l0 + 4];
    const float4 uv0 = *(const float4*)&urow[l0];
    const float4 uv1 = *(const float4*)&urow[l0 + 4];
    const float4 bv0 = *(const float4*)&Brow[l0];
    const float4 bv1 = *(const float4*)&Brow[l0 + 4];
    const float dvv[8] = {dv0.x, dv0.y, dv0.z, dv0.w, dv1.x, dv1.y, dv1.z, dv1.w};
    const float uvv[8] = {uv0.x, uv0.y, uv0.z, uv0.w, uv1.x, uv1.y, uv1.z, uv1.w};
    const float Bv[8] = {bv0.x, bv0.y, bv0.z, bv0.w, bv1.x, bv1.y, bv1.z, bv1.w};
#pragma unroll
    for (int j = 0; j < 8; ++j) {
      const float dl = dvv[j];
      const float da = exp2f(dl * a2);
      h = fmaf(da, h, dl * uvv[j] * Bv[j]);
      dsum += dl;
    }
  }
  hend[(size_t)gidx * 16 + n] = h;
  aprod[(size_t)gidx * 16 + n] = exp2f(a2 * dsum);
}

__global__ __launch_bounds__(256) void k_scanmid(
    const float* __restrict__ hend, const float* __restrict__ aprod,
    float* __restrict__ hinit) {
  const int gid = blockIdx.x * 256 + threadIdx.x;
  const int chain = gid >> 4, n = gid & 15;
  float H = 0.f;
  for (int c = 0; c < CH; ++c) {
    const size_t o = ((size_t)chain * CH + c) * 16 + n;
    hinit[o] = H;
    H = fmaf(aprod[o], H, hend[o]);
  }
}

__global__ __launch_bounds__(256) void k_scan2(
    const float* __restrict__ deltaT, const float* __restrict__ uT,
    const float* __restrict__ BCt, const float* __restrict__ resT,
    const float* __restrict__ A_log, const float* __restrict__ Dp,
    const float* __restrict__ hinit, float* __restrict__ yT) {
  const int tid = threadIdx.x;
  const int n = tid & 15, g = tid >> 4;
  const int gidx = blockIdx.x * 16 + g;
  const int chain = gidx / CH, c = gidx % CH;
  const int b = chain / DI, d = chain % DI;
  const float a2 = -expf(A_log[d * DSN + n]) * 1.44269504088896341f;
  const float dp = Dp[d];
  const int base = c * CLEN;
  const float* drow = deltaT + (size_t)chain * SL + base;
  const float* urow = uT + (size_t)chain * SL + base;
  const float* Brow = BCt + (size_t)(b * 32 + n) * SL + base;
  const float* Crow = BCt + (size_t)(b * 32 + 16 + n) * SL + base;
  const float* resb = resT + (size_t)chain * SL + base;
  float* yb = yT + (size_t)chain * SL + base;
  float h = hinit[(size_t)gidx * 16 + n];
  for (int l0 = 0; l0 < CLEN; l0 += 8) {
    const float4 dv0 = *(const float4*)&drow[l0];
    const float4 dv1 = *(const float4*)&drow[l0 + 4];
    const float4 uv0 = *(const float4*)&urow[l0];
    const float4 uv1 = *(const float4*)&urow[l0 + 4];
    const float4 bv0 = *(const float4*)&Brow[l0];
    const float4 bv1 = *(const float4*)&Brow[l0 + 4];
    const float4 cv0 = *(const float4*)&Crow[l0];
    const float4 cv1 = *(const float4*)&Crow[l0 + 4];
    const float dvv[8] = {dv0.x, dv0.y, dv0.z, dv0.w, dv1.x, dv1.y, dv1.z, dv1.w};
    const float uvv[8] = {uv0.x, uv0.y, uv0.z, uv0.w, uv1.x, uv1.y, uv1.z, uv1.w};
    const float Bv[8] = {bv0.x, bv0.y, bv0.z, bv0.w, bv1.x, bv1.y, bv1.z, bv1.w};
    const float Cv[8] = {cv0.x, cv0.y, cv0.z, cv0.w, cv1.x, cv1.y, cv1.z, cv1.w};
    float p[8];
#pragma unroll
    for (int j = 0; j < 8; ++j) {
      const float dl = dvv[j];
      const float da = exp2f(dl * a2);
      h = fmaf(da, h, dl * uvv[j] * Bv[j]);
      p[j] = h * Cv[j];
    }
#pragma unroll
    for (int j = 0; j < 8; ++j) p[j] += __shfl_xor(p[j], 1);
#pragma unroll
    for (int j = 0; j < 8; ++j) p[j] += __shfl_xor(p[j], 2);
#pragma unroll
    for (int j = 0; j < 8; ++j) p[j] += __shfl_xor(p[j], 4);
#pragma unroll
    for (int j = 0; j < 8; ++j) p[j] += __shfl_xor(p[j], 8);
    float myp = p[0], myu = uvv[0];
#pragma unroll
    for (int j = 1; j < 8; ++j) {
      const bool e = (n == j);
      myp = e ? p[j] : myp;
      myu = e ? uvv[j] : myu;
    }
    if (n < 8) {
      const float r = resb[l0 + n];
      yb[l0 + n] = (myp + myu * dp) * siluf(r);
    }
  }
}

// ---------------- RMS denom ----------------
__global__ void k_rinv(const float* __restrict__ t, float* __restrict__ rinv) {
  const int row = blockIdx.x;
  const float* tr = t + (size_t)row * DM;
  const int tid = threadIdx.x;
  float ss = 0.f;
#pragma unroll
  for (int k = 0; k < DM / 64; ++k) {
    const float v = tr[tid + k * 64];
    ss = fmaf(v, v, ss);
  }
  ss += __shfl_xor(ss, 1);
  ss += __shfl_xor(ss, 2);
  ss += __shfl_xor(ss, 4);
  ss += __shfl_xor(ss, 8);
  ss += __shfl_xor(ss, 16);
  ss += __shfl_xor(ss, 32);
  if (tid == 0) rinv[row] = 1.f / sqrtf(ss / DM + 1e-5f);
}

// ---------------- pooled partial sums ----------------
__global__ void k_pool(const float* __restrict__ t, const float* __restrict__ rinv,
                       float* __restrict__ part) {
  const int b = blockIdx.x, dmb = blockIdx.y, ch = blockIdx.z;
  const int dm = dmb * 64 + threadIdx.x;
  const int lbeg = ch * (SL / 32);
  float s = 0.f;
  for (int l = lbeg; l < lbeg + SL / 32; ++l)
    s = fmaf(t[((size_t)b * SL + l) * DM + dm], rinv[b * SL + l], s);
  part[((size_t)ch * NB + b) * DM + dm] = s;
}

// ---------------- head ----------------
__global__ void k_head(const float* __restrict__ part, const float* __restrict__ norm_w,
                       const float* __restrict__ hw, const float* __restrict__ hb,
                       float* __restrict__ out) {
  const int b = blockIdx.x;
  const int tid = threadIdx.x;
  __shared__ float pv[DM];
  for (int k = tid; k < DM; k += 64) {
    float s = 0.f;
#pragma unroll
    for (int c = 0; c < 32; ++c) s += part[((size_t)c * NB + b) * DM + k];
    pv[k] = s * norm_w[k] * (1.f / SL);
  }
  __syncthreads();
  const int cls = blockIdx.y * 64 + tid;
  if (cls < NCLS) {
    const float* wr = hw + (size_t)cls * DM;
    float acc = hb[cls];
#pragma unroll 4
    for (int k = 0; k < DM; k += 4) {
      const float4 w4 = *(const float4*)&wr[k];
      acc = fmaf(pv[k], w4.x, acc);
      acc = fmaf(pv[k + 1], w4.y, acc);
      acc = fmaf(pv[k + 2], w4.z, acc);
      acc = fmaf(pv[k + 3], w4.w, acc);
    }
    out[(size_t)b * NCLS + cls] = acc;
  }
}

extern "C" void kernel_launch(void* const* d_in, const int* in_sizes, int n_in,
                              void* d_out, int out_size, void* d_ws, size_t ws_size,
                              hipStream_t stream) {
  (void)in_sizes; (void)n_in; (void)out_size; (void)ws_size;
  const float* x = (const float*)d_in[0];
  const float* patch_w = (const float*)d_in[1];
  const float* patch_b = (const float*)d_in[2];
  const float* in_proj_w = (const float*)d_in[3];
  const float* conv_w = (const float*)d_in[4];
  const float* conv_b = (const float*)d_in[5];
  const float* x_proj_w = (const float*)d_in[6];
  const float* dt_proj_w = (const float*)d_in[7];
  const float* dt_proj_b = (const float*)d_in[8];
  const float* A_log = (const float*)d_in[9];
  const float* Dp = (const float*)d_in[10];
  const float* out_proj_w = (const float*)d_in[11];
  const float* norm_w = (const float*)d_in[12];
  const float* head_w = (const float*)d_in[13];
  const float* head_b = (const float*)d_in[14];

  float* ws = (float*)d_ws;
  size_t o = 0;
  float* t = ws + o;     o += (size_t)NB * SL * DM;
  float* xcT = ws + o;   o += (size_t)NB * DI * SL;
  float* resT = ws + o;  o += (size_t)NB * DI * SL;
  float* uT = ws + o;    o += (size_t)NB * DI * SL;
  float* dltT = ws + o;  o += (size_t)NB * DI * SL;
  float* yT = ws + o;    o += (size_t)NB * DI * SL;
  float* dbl24 = ws + o; o += (size_t)NB * SL * DR;
  float* BCt = ws + o;   o += (size_t)NB * 32 * SL;
  float* rinv = ws + o;  o += (size_t)NB * SL;
  float* part = ws + o;  o += (size_t)32 * NB * DM;
  float* hend = ws + o;  o += (size_t)NG * 16;
  float* aprod = ws + o; o += (size_t)NG * 16;
  float* hinit = ws + o; o += (size_t)NG * 16;
  unsigned short* tb = (unsigned short*)(ws + o); o += (size_t)NB * SL * DM / 2;

  k_patch<<<NB * SL, 128, 0, stream>>>(x, patch_w, patch_b, t, tb);

  for (int i = 0; i < NLAYER; ++i) {
    // in_proj: tb[M,384](bf16) x W[1536,384]^T -> xcT / resT ([b][n][l] fp32)
    k_mgemm<128, 128, 1, 1536, false><<<dim3(98, 12), 256, 0, stream>>>(
        tb, nullptr, in_proj_w + (size_t)i * 2 * DI * DM, xcT, resT, nullptr, DM);
    // depthwise causal conv + silu -> uT
    k_conv<<<(NB * DI * SL / 4) / 256, 256, 0, stream>>>(
        xcT, conv_w + (size_t)i * DI * 4, conv_b + (size_t)i * DI, uT);
    // x_proj: uT (AT-staged bf16) x W[56,768]^T -> dbl24 + BCt
    k_mgemm<64, 64, 0, XPN, true><<<dim3(196, 1), 256, 0, stream>>>(
        nullptr, uT, x_proj_w + (size_t)i * XPN * DI, dbl24, BCt, nullptr, DI);
    // dt_proj (fp32 SIMT): softplus(dbl24 @ dt_w^T + b) -> dltT [b][d][l]
    k_gemm<2, true, 64><<<dim3(196, 12), 256, 0, stream>>>(
        dbl24, dt_proj_w + (size_t)i * DI * DR, dt_proj_b + (size_t)i * DI, dltT,
        DR, DR);
    // chunked selective scan + gate -> yT
    k_scan1<<<NG / 16, 256, 0, stream>>>(
        dltT, uT, BCt, A_log + (size_t)i * DI * DSN, hend, aprod);
    k_scanmid<<<(NCHAIN * 16) / 256, 256, 0, stream>>>(hend, aprod, hinit);
    k_scan2<<<NG / 16, 256, 0, stream>>>(
        dltT, uT, BCt, resT, A_log + (size_t)i * DI * DSN, Dp + (size_t)i * DI,
        hinit, yT);
    // out_proj: yT (AT-staged bf16) x W[384,768]^T -> t += ; tb = bf16(t)
    k_mgemm<128, 128, 2, 384, true><<<dim3(98, 3), 256, 0, stream>>>(
        nullptr, yT, out_proj_w + (size_t)i * DM * DI, t, nullptr, tb, DI);
  }

  k_rinv<<<NB * SL, 64, 0, stream>>>(t, rinv);
  k_pool<<<dim3(NB, DM / 64, 32), 64, 0, stream>>>(t, rinv, part);
  k_head<<<dim3(NB, 16), 64, 0, stream>>>(part, norm_w, head_w, head_b, (float*)d_out);
}

// Round 6
// 1676.951 us; speedup vs baseline: 1.3301x; 1.3301x over previous
//
#include <hip/hip_runtime.h>
#include <math.h>

// CausalVisionMamba — round 6: compact BC[b][l][32] (n-fast) for scan,
// CH=14 restored; AT-staged MFMA GEMMs; vectorized conv.

namespace {
constexpr int NB = 4;
constexpr int SL = 3136;
constexpr int DM = 384;
constexpr int DI = 768;
constexpr int DSN = 16;
constexpr int DR = 24;
constexpr int NLAYER = 4;
constexpr int NCLS = 1000;
constexpr int XPN = DR + 2 * DSN;  // 56
constexpr int CH = 14;
constexpr int CLEN = SL / CH;      // 224
constexpr int NCHAIN = NB * DI;    // 3072
constexpr int NG = NCHAIN * CH;    // 43008
}

typedef float f32x4 __attribute__((ext_vector_type(4)));
typedef short short8 __attribute__((ext_vector_type(8)));
typedef short short4v __attribute__((ext_vector_type(4)));

__device__ __forceinline__ float siluf(float x) { return x / (1.f + expf(-x)); }
__device__ __forceinline__ float softplusf(float x) {
  return fmaxf(x, 0.f) + log1pf(expf(-fabsf(x)));
}
__device__ __forceinline__ unsigned short cvt_bf(float f) {
  unsigned int x = __float_as_uint(f);
  unsigned int r = (x + 0x7fffu + ((x >> 16) & 1u)) >> 16;  // RNE
  return (unsigned short)r;
}

// ---------------- patch embed: t[b][l][dm] fp32 + tb bf16 ----------------
__global__ void k_patch(const float* __restrict__ x, const float* __restrict__ w,
                        const float* __restrict__ bias, float* __restrict__ t,
                        unsigned short* __restrict__ tb) {
  const int blk = blockIdx.x;
  const int b = blk / SL, l = blk % SL;
  const int hh = l / 56, ww = l % 56;
  __shared__ float patch[48];
  const int tid = threadIdx.x;
  if (tid < 48) {
    const int c = tid / 16, kh = (tid % 16) / 4, kw = tid % 4;
    patch[tid] = x[((size_t)(b * 3 + c) * 224 + (hh * 4 + kh)) * 224 + (ww * 4 + kw)];
  }
  __syncthreads();
  for (int dm = tid; dm < DM; dm += 128) {
    const float* wr = w + (size_t)dm * 48;
    float acc = bias[dm];
#pragma unroll
    for (int p = 0; p < 48; ++p) acc = fmaf(patch[p], wr[p], acc);
    const size_t o = ((size_t)b * SL + l) * DM + dm;
    t[o] = acc;
    tb[o] = cvt_bf(acc);
  }
}

// ---------------- bf16 MFMA GEMM: D = A[M,K](bf16) * W[N,K]^T(fp32->bf16) -------
// AT=false: A is bf16 [M][K] row-major.
// AT=true : A is fp32 [B][K][SL]; staged with fused transpose + bf16 cvt.
// MEPI 0: x_proj  -> n<DR: out=dbl24[m][24]; DR<=n<NCAP: out2=BC[m][32] (n-DR fast)
// MEPI 1: in_proj -> n<DI: out=xcT [b][n][l]; n>=DI: out2=resT [b][n][l]
// MEPI 2: out_proj-> out[m*DM+n] += acc (t) and outb = bf16(new t)
template <int BM, int BN, int MEPI, int NCAP, bool AT>
__global__ __launch_bounds__(256) void k_mgemm(
    const unsigned short* __restrict__ A, const float* __restrict__ Afp,
    const float* __restrict__ W, float* __restrict__ out,
    float* __restrict__ out2, unsigned short* __restrict__ outb, const int K) {
  constexpr int WM = BM / 2, WN = BN / 2, FM = WM / 16, FN = WN / 16;
  constexpr bool NMASK = (NCAP % BN) != 0;
  __shared__ unsigned short As[BM * 40];
  __shared__ unsigned short Bs[BN * 40];
  const int tid = threadIdx.x;
  const int lane = tid & 63, wave = tid >> 6;
  const int wm = wave >> 1, wn = wave & 1;
  const int m0 = blockIdx.x * BM, n0 = blockIdx.y * BN;
  const int r16 = lane & 15, kg = (lane >> 4) * 8;
  f32x4 acc[FM][FN] = {};
  const int nk = K >> 5;
  for (int kt = 0; kt < nk; ++kt) {
    const int k0 = kt << 5;
    if constexpr (AT) {
      // fp32 [B][K][SL] -> bf16 LDS [m][k], fused transpose.
#pragma unroll
      for (int it = 0; it < BM / 64; ++it) {
        const int c = tid + 256 * it;
        const int kp = c & 15;
        const int lq = (c >> 4) * 4;
        const int mrow = m0 + lq;
        const int bb = mrow / SL;
        const size_t rowo = (size_t)(bb * K + k0 + 2 * kp) * SL + (mrow - bb * SL);
        const float4 v0 = *(const float4*)&Afp[rowo];
        const float4 v1 = *(const float4*)&Afp[rowo + SL];
        const float ve0[4] = {v0.x, v0.y, v0.z, v0.w};
        const float ve1[4] = {v1.x, v1.y, v1.z, v1.w};
#pragma unroll
        for (int e = 0; e < 4; ++e) {
          const unsigned int pk =
              (unsigned int)cvt_bf(ve0[e]) | ((unsigned int)cvt_bf(ve1[e]) << 16);
          *(unsigned int*)&As[(lq + e) * 40 + 2 * kp] = pk;
        }
      }
    } else {
#pragma unroll
      for (int it = 0; it < (BM * 4) / 256; ++it) {
        const int c = tid + 256 * it;
        const int row = c >> 2, ks = (c & 3) * 8;
        *(short8*)&As[row * 40 + ks] =
            *(const short8*)&A[(size_t)(m0 + row) * K + k0 + ks];
      }
    }
    // B staging: fp32 global -> cvt -> LDS
#pragma unroll
    for (int it = 0; it < (BN * 8) / 256; ++it) {
      const int c = tid + 256 * it;
      const int row = c >> 3, ks = (c & 7) * 4;
      float4 v = make_float4(0.f, 0.f, 0.f, 0.f);
      if (!NMASK || (n0 + row) < NCAP)
        v = *(const float4*)&W[(size_t)(n0 + row) * K + k0 + ks];
      short4v o4;
      o4[0] = (short)cvt_bf(v.x);
      o4[1] = (short)cvt_bf(v.y);
      o4[2] = (short)cvt_bf(v.z);
      o4[3] = (short)cvt_bf(v.w);
      *(short4v*)&Bs[row * 40 + ks] = o4;
    }
    __syncthreads();
    short8 af[FM], bfv[FN];
#pragma unroll
    for (int i = 0; i < FM; ++i)
      af[i] = *(const short8*)&As[(wm * WM + i * 16 + r16) * 40 + kg];
#pragma unroll
    for (int j = 0; j < FN; ++j)
      bfv[j] = *(const short8*)&Bs[(wn * WN + j * 16 + r16) * 40 + kg];
#pragma unroll
    for (int i = 0; i < FM; ++i)
#pragma unroll
      for (int j = 0; j < FN; ++j)
        acc[i][j] = __builtin_amdgcn_mfma_f32_16x16x32_bf16(af[i], bfv[j],
                                                            acc[i][j], 0, 0, 0);
    __syncthreads();
  }

  // Epilogue. C/D layout: col n = lane&15, rows m = (lane>>4)*4 + r.
#pragma unroll
  for (int i = 0; i < FM; ++i) {
#pragma unroll
    for (int j = 0; j < FN; ++j) {
      const int n = n0 + wn * WN + j * 16 + r16;
      const int mb = m0 + wm * WM + i * 16 + ((lane >> 4) << 2);
      f32x4 a = acc[i][j];
      if (MEPI == 0) {
        if (n < DR) {
#pragma unroll
          for (int r = 0; r < 4; ++r) out[(size_t)(mb + r) * DR + n] = a[r];
        } else if (n < NCAP) {
#pragma unroll
          for (int r = 0; r < 4; ++r) out2[(size_t)(mb + r) * 32 + (n - DR)] = a[r];
        }
      } else if (MEPI == 1) {
        float* base = out;
        int nn = n;
        if (n >= DI) { base = out2; nn = n - DI; }
        const int bb = mb / SL;
        const int ll = mb - bb * SL;
        *(f32x4*)&base[((size_t)(bb * DI + nn)) * SL + ll] = a;
      } else {  // MEPI 2
#pragma unroll
        for (int r = 0; r < 4; ++r) {
          const size_t off = (size_t)(mb + r) * DM + n;
          const float nv = out[off] + a[r];
          out[off] = nv;
          outb[off] = cvt_bf(nv);
        }
      }
    }
  }
}

// ---------------- fp32 SIMT GEMM (dt_proj, K=24) ----------------
template <int EPI, bool KTAIL, int NCAP>
__global__ __launch_bounds__(256) void k_gemm(
    const float* __restrict__ A, const float* __restrict__ W,
    const float* __restrict__ bias, float* __restrict__ out, int K, int lda) {
  __shared__ float sm[4352];
  const int tid = threadIdx.x;
  const int m0 = blockIdx.x * 64;
  const int n0 = blockIdx.y * 64;
  const int b = m0 / SL, l0 = m0 % SL;
  const int tm = tid >> 4, tn = tid & 15;
  float acc[4][4] = {};
  float* As = sm;
  float* Ws = sm + 16 * 68;

  const int nk = (K + 15) / 16;
  for (int kt = 0; kt < nk; ++kt) {
    const int k0 = kt * 16;
    {
      const int row = tid >> 2;
      const int kq = (tid & 3) * 4;
      const int kb = k0 + kq;
      float4 v = make_float4(0.f, 0.f, 0.f, 0.f);
      if (!KTAIL || kb < K) v = *(const float4*)&A[(size_t)(m0 + row) * lda + kb];
      As[(kq + 0) * 68 + row] = v.x;
      As[(kq + 1) * 68 + row] = v.y;
      As[(kq + 2) * 68 + row] = v.z;
      As[(kq + 3) * 68 + row] = v.w;
    }
    {
      const int row = tid >> 2;
      const int kq = (tid & 3) * 4;
      const int kb = k0 + kq;
      float4 v = make_float4(0.f, 0.f, 0.f, 0.f);
      const bool nok = (NCAP % 64 == 0) || (n0 + row < NCAP);
      if (nok && (!KTAIL || kb < K)) v = *(const float4*)&W[(size_t)(n0 + row) * K + kb];
      Ws[(kq + 0) * 68 + row] = v.x;
      Ws[(kq + 1) * 68 + row] = v.y;
      Ws[(kq + 2) * 68 + row] = v.z;
      Ws[(kq + 3) * 68 + row] = v.w;
    }
    __syncthreads();
#pragma unroll
    for (int kk = 0; kk < 16; ++kk) {
      const float4 av = *(const float4*)&As[kk * 68 + 4 * tm];
      const float4 wv = *(const float4*)&Ws[kk * 68 + 4 * tn];
      const float ax[4] = {av.x, av.y, av.z, av.w};
      const float wx[4] = {wv.x, wv.y, wv.z, wv.w};
#pragma unroll
      for (int i = 0; i < 4; ++i)
#pragma unroll
        for (int j = 0; j < 4; ++j) acc[i][j] = fmaf(ax[i], wx[j], acc[i][j]);
    }
    __syncthreads();
  }

  // transpose epilogue through LDS -> [b][n][l] (EPI==2: softplus+bias)
#pragma unroll
  for (int j = 0; j < 4; ++j) {
    const int nn = 4 * tn + j;
#pragma unroll
    for (int i = 0; i < 4; ++i) {
      float v = acc[i][j];
      if (EPI == 2) v = softplusf(v + bias[n0 + nn]);
      sm[nn * 68 + 4 * tm + i] = v;
    }
  }
  __syncthreads();
  const int row = tid >> 2;
  const int seg = (tid & 3) * 16;
  const float* src = &sm[row * 68 + seg];
  float* dst = out + ((size_t)(b * DI + n0 + row)) * SL + l0 + seg;
#pragma unroll
  for (int q = 0; q < 4; ++q) {
    *(float4*)&dst[q * 4] = *(const float4*)&src[q * 4];
  }
}

// ---------------- depthwise causal conv1d + bias + silu (4 l per thread) --------
__global__ void k_conv(const float* __restrict__ xcT, const float* __restrict__ cw,
                       const float* __restrict__ cb, float* __restrict__ uT) {
  const size_t idx = (size_t)blockIdx.x * 256 + threadIdx.x;
  const int l4 = (int)(idx % (SL / 4)) * 4;
  const int bd = (int)(idx / (SL / 4));
  const int d = bd % DI;
  const float* row = xcT + (size_t)bd * SL;
  const float4 w = *(const float4*)&cw[d * 4];
  const float4 cur = *(const float4*)&row[l4];
  float p1 = 0.f, p2 = 0.f, p3 = 0.f;
  if (l4 > 0) {
    const float4 pv = *(const float4*)&row[l4 - 4];
    p1 = pv.y; p2 = pv.z; p3 = pv.w;
  }
  const float cbd = cb[d];
  float4 o;
  o.x = cbd + w.w * cur.x + w.z * p3 + w.y * p2 + w.x * p1;
  o.y = cbd + w.w * cur.y + w.z * cur.x + w.y * p3 + w.x * p2;
  o.z = cbd + w.w * cur.z + w.z * cur.y + w.y * cur.x + w.x * p3;
  o.w = cbd + w.w * cur.w + w.z * cur.z + w.y * cur.y + w.x * cur.x;
  o.x = siluf(o.x); o.y = siluf(o.y); o.z = siluf(o.z); o.w = siluf(o.w);
  *(float4*)&uT[(size_t)bd * SL + l4] = o;
}

// ---------------- chunked selective scan (BC layout: [b][l][32], n-fast) --------
__global__ __launch_bounds__(256) void k_scan1(
    const float* __restrict__ deltaT, const float* __restrict__ uT,
    const float* __restrict__ BC, const float* __restrict__ A_log,
    float* __restrict__ hend, float* __restrict__ aprod) {
  const int tid = threadIdx.x;
  const int n = tid & 15, g = tid >> 4;
  const int gidx = blockIdx.x * 16 + g;
  const int chain = gidx / CH, c = gidx % CH;
  const int b = chain / DI, d = chain % DI;
  const float a2 = -expf(A_log[d * DSN + n]) * 1.44269504088896341f;
  const int base = c * CLEN;
  const float* drow = deltaT + (size_t)chain * SL + base;
  const float* urow = uT + (size_t)chain * SL + base;
  const float* bcb = BC + ((size_t)b * SL + base) * 32 + n;
  float h = 0.f, dsum = 0.f;
  for (int l0 = 0; l0 < CLEN; l0 += 8) {
    const float4 dv0 = *(const float4*)&drow[l0];
    const float4 dv1 = *(const float4*)&drow[l0 + 4];
    const float4 uv0 = *(const float4*)&urow[l0];
    const float4 uv1 = *(const float4*)&urow[l0 + 4];
    float Bv[8];
#pragma unroll
    for (int j = 0; j < 8; ++j) Bv[j] = bcb[(size_t)(l0 + j) * 32];
    const float dvv[8] = {dv0.x, dv0.y, dv0.z, dv0.w, dv1.x, dv1.y, dv1.z, dv1.w};
    const float uvv[8] = {uv0.x, uv0.y, uv0.z, uv0.w, uv1.x, uv1.y, uv1.z, uv1.w};
#pragma unroll
    for (int j = 0; j < 8; ++j) {
      const float dl = dvv[j];
      const float da = exp2f(dl * a2);
      h = fmaf(da, h, dl * uvv[j] * Bv[j]);
      dsum += dl;
    }
  }
  hend[(size_t)gidx * 16 + n] = h;
  aprod[(size_t)gidx * 16 + n] = exp2f(a2 * dsum);
}

__global__ __launch_bounds__(256) void k_scanmid(
    const float* __restrict__ hend, const float* __restrict__ aprod,
    float* __restrict__ hinit) {
  const int gid = blockIdx.x * 256 + threadIdx.x;
  const int chain = gid >> 4, n = gid & 15;
  float H = 0.f;
  for (int c = 0; c < CH; ++c) {
    const size_t o = ((size_t)chain * CH + c) * 16 + n;
    hinit[o] = H;
    H = fmaf(aprod[o], H, hend[o]);
  }
}

__global__ __launch_bounds__(256) void k_scan2(
    const float* __restrict__ deltaT, const float* __restrict__ uT,
    const float* __restrict__ BC, const float* __restrict__ resT,
    const float* __restrict__ A_log, const float* __restrict__ Dp,
    const float* __restrict__ hinit, float* __restrict__ yT) {
  const int tid = threadIdx.x;
  const int n = tid & 15, g = tid >> 4;
  const int gidx = blockIdx.x * 16 + g;
  const int chain = gidx / CH, c = gidx % CH;
  const int b = chain / DI, d = chain % DI;
  const float a2 = -expf(A_log[d * DSN + n]) * 1.44269504088896341f;
  const float dp = Dp[d];
  const int base = c * CLEN;
  const float* drow = deltaT + (size_t)chain * SL + base;
  const float* urow = uT + (size_t)chain * SL + base;
  const float* bcb = BC + ((size_t)b * SL + base) * 32 + n;
  const float* resb = resT + (size_t)chain * SL + base;
  float* yb = yT + (size_t)chain * SL + base;
  float h = hinit[(size_t)gidx * 16 + n];
  for (int l0 = 0; l0 < CLEN; l0 += 8) {
    const float4 dv0 = *(const float4*)&drow[l0];
    const float4 dv1 = *(const float4*)&drow[l0 + 4];
    const float4 uv0 = *(const float4*)&urow[l0];
    const float4 uv1 = *(const float4*)&urow[l0 + 4];
    float Bv[8], Cv[8];
#pragma unroll
    for (int j = 0; j < 8; ++j) {
      Bv[j] = bcb[(size_t)(l0 + j) * 32];
      Cv[j] = bcb[(size_t)(l0 + j) * 32 + 16];
    }
    const float dvv[8] = {dv0.x, dv0.y, dv0.z, dv0.w, dv1.x, dv1.y, dv1.z, dv1.w};
    const float uvv[8] = {uv0.x, uv0.y, uv0.z, uv0.w, uv1.x, uv1.y, uv1.z, uv1.w};
    float p[8];
#pragma unroll
    for (int j = 0; j < 8; ++j) {
      const float dl = dvv[j];
      const float da = exp2f(dl * a2);
      h = fmaf(da, h, dl * uvv[j] * Bv[j]);
      p[j] = h * Cv[j];
    }
#pragma unroll
    for (int j = 0; j < 8; ++j) p[j] += __shfl_xor(p[j], 1);
#pragma unroll
    for (int j = 0; j < 8; ++j) p[j] += __shfl_xor(p[j], 2);
#pragma unroll
    for (int j = 0; j < 8; ++j) p[j] += __shfl_xor(p[j], 4);
#pragma unroll
    for (int j = 0; j < 8; ++j) p[j] += __shfl_xor(p[j], 8);
    float myp = p[0], myu = uvv[0];
#pragma unroll
    for (int j = 1; j < 8; ++j) {
      const bool e = (n == j);
      myp = e ? p[j] : myp;
      myu = e ? uvv[j] : myu;
    }
    if (n < 8) {
      const float r = resb[l0 + n];
      yb[l0 + n] = (myp + myu * dp) * siluf(r);
    }
  }
}

// ---------------- RMS denom ----------------
__global__ void k_rinv(const float* __restrict__ t, float* __restrict__ rinv) {
  const int row = blockIdx.x;
  const float* tr = t + (size_t)row * DM;
  const int tid = threadIdx.x;
  float ss = 0.f;
#pragma unroll
  for (int k = 0; k < DM / 64; ++k) {
    const float v = tr[tid + k * 64];
    ss = fmaf(v, v, ss);
  }
  ss += __shfl_xor(ss, 1);
  ss += __shfl_xor(ss, 2);
  ss += __shfl_xor(ss, 4);
  ss += __shfl_xor(ss, 8);
  ss += __shfl_xor(ss, 16);
  ss += __shfl_xor(ss, 32);
  if (tid == 0) rinv[row] = 1.f / sqrtf(ss / DM + 1e-5f);
}

// ---------------- pooled partial sums ----------------
__global__ void k_pool(const float* __restrict__ t, const float* __restrict__ rinv,
                       float* __restrict__ part) {
  const int b = blockIdx.x, dmb = blockIdx.y, ch = blockIdx.z;
  const int dm = dmb * 64 + threadIdx.x;
  const int lbeg = ch * (SL / 32);
  float s = 0.f;
  for (int l = lbeg; l < lbeg + SL / 32; ++l)
    s = fmaf(t[((size_t)b * SL + l) * DM + dm], rinv[b * SL + l], s);
  part[((size_t)ch * NB + b) * DM + dm] = s;
}

// ---------------- head ----------------
__global__ void k_head(const float* __restrict__ part, const float* __restrict__ norm_w,
                       const float* __restrict__ hw, const float* __restrict__ hb,
                       float* __restrict__ out) {
  const int b = blockIdx.x;
  const int tid = threadIdx.x;
  __shared__ float pv[DM];
  for (int k = tid; k < DM; k += 64) {
    float s = 0.f;
#pragma unroll
    for (int c = 0; c < 32; ++c) s += part[((size_t)c * NB + b) * DM + k];
    pv[k] = s * norm_w[k] * (1.f / SL);
  }
  __syncthreads();
  const int cls = blockIdx.y * 64 + tid;
  if (cls < NCLS) {
    const float* wr = hw + (size_t)cls * DM;
    float acc = hb[cls];
#pragma unroll 4
    for (int k = 0; k < DM; k += 4) {
      const float4 w4 = *(const float4*)&wr[k];
      acc = fmaf(pv[k], w4.x, acc);
      acc = fmaf(pv[k + 1], w4.y, acc);
      acc = fmaf(pv[k + 2], w4.z, acc);
      acc = fmaf(pv[k + 3], w4.w, acc);
    }
    out[(size_t)b * NCLS + cls] = acc;
  }
}

extern "C" void kernel_launch(void* const* d_in, const int* in_sizes, int n_in,
                              void* d_out, int out_size, void* d_ws, size_t ws_size,
                              hipStream_t stream) {
  (void)in_sizes; (void)n_in; (void)out_size; (void)ws_size;
  const float* x = (const float*)d_in[0];
  const float* patch_w = (const float*)d_in[1];
  const float* patch_b = (const float*)d_in[2];
  const float* in_proj_w = (const float*)d_in[3];
  const float* conv_w = (const float*)d_in[4];
  const float* conv_b = (const float*)d_in[5];
  const float* x_proj_w = (const float*)d_in[6];
  const float* dt_proj_w = (const float*)d_in[7];
  const float* dt_proj_b = (const float*)d_in[8];
  const float* A_log = (const float*)d_in[9];
  const float* Dp = (const float*)d_in[10];
  const float* out_proj_w = (const float*)d_in[11];
  const float* norm_w = (const float*)d_in[12];
  const float* head_w = (const float*)d_in[13];
  const float* head_b = (const float*)d_in[14];

  float* ws = (float*)d_ws;
  size_t o = 0;
  float* t = ws + o;     o += (size_t)NB * SL * DM;
  float* xcT = ws + o;   o += (size_t)NB * DI * SL;
  float* resT = ws + o;  o += (size_t)NB * DI * SL;
  float* uT = ws + o;    o += (size_t)NB * DI * SL;
  float* dltT = ws + o;  o += (size_t)NB * DI * SL;
  float* yT = ws + o;    o += (size_t)NB * DI * SL;
  float* dbl24 = ws + o; o += (size_t)NB * SL * DR;
  float* BC = ws + o;    o += (size_t)NB * SL * 32;
  float* rinv = ws + o;  o += (size_t)NB * SL;
  float* part = ws + o;  o += (size_t)32 * NB * DM;
  float* hend = ws + o;  o += (size_t)NG * 16;
  float* aprod = ws + o; o += (size_t)NG * 16;
  float* hinit = ws + o; o += (size_t)NG * 16;
  unsigned short* tb = (unsigned short*)(ws + o); o += (size_t)NB * SL * DM / 2;

  k_patch<<<NB * SL, 128, 0, stream>>>(x, patch_w, patch_b, t, tb);

  for (int i = 0; i < NLAYER; ++i) {
    // in_proj: tb[M,384](bf16) x W[1536,384]^T -> xcT / resT ([b][n][l] fp32)
    k_mgemm<128, 128, 1, 1536, false><<<dim3(98, 12), 256, 0, stream>>>(
        tb, nullptr, in_proj_w + (size_t)i * 2 * DI * DM, xcT, resT, nullptr, DM);
    // depthwise causal conv + silu -> uT
    k_conv<<<(NB * DI * SL / 4) / 256, 256, 0, stream>>>(
        xcT, conv_w + (size_t)i * DI * 4, conv_b + (size_t)i * DI, uT);
    // x_proj: uT (AT-staged bf16) x W[56,768]^T -> dbl24 + BC[b][l][32]
    k_mgemm<64, 64, 0, XPN, true><<<dim3(196, 1), 256, 0, stream>>>(
        nullptr, uT, x_proj_w + (size_t)i * XPN * DI, dbl24, BC, nullptr, DI);
    // dt_proj (fp32 SIMT): softplus(dbl24 @ dt_w^T + b) -> dltT [b][d][l]
    k_gemm<2, true, 64><<<dim3(196, 12), 256, 0, stream>>>(
        dbl24, dt_proj_w + (size_t)i * DI * DR, dt_proj_b + (size_t)i * DI, dltT,
        DR, DR);
    // chunked selective scan + gate -> yT
    k_scan1<<<NG / 16, 256, 0, stream>>>(
        dltT, uT, BC, A_log + (size_t)i * DI * DSN, hend, aprod);
    k_scanmid<<<(NCHAIN * 16) / 256, 256, 0, stream>>>(hend, aprod, hinit);
    k_scan2<<<NG / 16, 256, 0, stream>>>(
        dltT, uT, BC, resT, A_log + (size_t)i * DI * DSN, Dp + (size_t)i * DI,
        hinit, yT);
    // out_proj: yT (AT-staged bf16) x W[384,768]^T -> t += ; tb = bf16(t)
    k_mgemm<128, 128, 2, 384, true><<<dim3(98, 3), 256, 0, stream>>>(
        nullptr, yT, out_proj_w + (size_t)i * DM * DI, t, nullptr, tb, DI);
  }

  k_rinv<<<NB * SL, 64, 0, stream>>>(t, rinv);
  k_pool<<<dim3(NB, DM / 64, 32), 64, 0, stream>>>(t, rinv, part);
  k_head<<<dim3(NB, 16), 64, 0, stream>>>(part, norm_w, head_w, head_b, (float*)d_out);
}

// Round 7
// 1519.369 us; speedup vs baseline: 1.4680x; 1.1037x over previous
//
#include <hip/hip_runtime.h>
#include <math.h>

// CausalVisionMamba — round 7: fused single-kernel hierarchical scan (k_scanf);
// register-cached da/dbu, LDS Hillis-Steele across 16 groups, serial tile carry.

namespace {
constexpr int NB = 4;
constexpr int SL = 3136;
constexpr int DM = 384;
constexpr int DI = 768;
constexpr int DSN = 16;
constexpr int DR = 24;
constexpr int NLAYER = 4;
constexpr int NCLS = 1000;
constexpr int XPN = DR + 2 * DSN;  // 56
constexpr int NCHAIN = NB * DI;    // 3072
constexpr int NGRP = 16;           // groups per block
constexpr int KS = 14;             // steps per group per tile
constexpr int TILE = NGRP * KS;    // 224
}

typedef float f32x4 __attribute__((ext_vector_type(4)));
typedef short short8 __attribute__((ext_vector_type(8)));
typedef short short4v __attribute__((ext_vector_type(4)));

__device__ __forceinline__ float siluf(float x) { return x / (1.f + expf(-x)); }
__device__ __forceinline__ float softplusf(float x) {
  return fmaxf(x, 0.f) + log1pf(expf(-fabsf(x)));
}
__device__ __forceinline__ unsigned short cvt_bf(float f) {
  unsigned int x = __float_as_uint(f);
  unsigned int r = (x + 0x7fffu + ((x >> 16) & 1u)) >> 16;  // RNE
  return (unsigned short)r;
}

// ---------------- patch embed: t[b][l][dm] fp32 + tb bf16 ----------------
__global__ void k_patch(const float* __restrict__ x, const float* __restrict__ w,
                        const float* __restrict__ bias, float* __restrict__ t,
                        unsigned short* __restrict__ tb) {
  const int blk = blockIdx.x;
  const int b = blk / SL, l = blk % SL;
  const int hh = l / 56, ww = l % 56;
  __shared__ float patch[48];
  const int tid = threadIdx.x;
  if (tid < 48) {
    const int c = tid / 16, kh = (tid % 16) / 4, kw = tid % 4;
    patch[tid] = x[((size_t)(b * 3 + c) * 224 + (hh * 4 + kh)) * 224 + (ww * 4 + kw)];
  }
  __syncthreads();
  for (int dm = tid; dm < DM; dm += 128) {
    const float* wr = w + (size_t)dm * 48;
    float acc = bias[dm];
#pragma unroll
    for (int p = 0; p < 48; ++p) acc = fmaf(patch[p], wr[p], acc);
    const size_t o = ((size_t)b * SL + l) * DM + dm;
    t[o] = acc;
    tb[o] = cvt_bf(acc);
  }
}

// ---------------- bf16 MFMA GEMM: D = A[M,K](bf16) * W[N,K]^T(fp32->bf16) -------
template <int BM, int BN, int MEPI, int NCAP, bool AT>
__global__ __launch_bounds__(256) void k_mgemm(
    const unsigned short* __restrict__ A, const float* __restrict__ Afp,
    const float* __restrict__ W, float* __restrict__ out,
    float* __restrict__ out2, unsigned short* __restrict__ outb, const int K) {
  constexpr int WM = BM / 2, WN = BN / 2, FM = WM / 16, FN = WN / 16;
  constexpr bool NMASK = (NCAP % BN) != 0;
  __shared__ unsigned short As[BM * 40];
  __shared__ unsigned short Bs[BN * 40];
  const int tid = threadIdx.x;
  const int lane = tid & 63, wave = tid >> 6;
  const int wm = wave >> 1, wn = wave & 1;
  const int m0 = blockIdx.x * BM, n0 = blockIdx.y * BN;
  const int r16 = lane & 15, kg = (lane >> 4) * 8;
  f32x4 acc[FM][FN] = {};
  const int nk = K >> 5;
  for (int kt = 0; kt < nk; ++kt) {
    const int k0 = kt << 5;
    if constexpr (AT) {
#pragma unroll
      for (int it = 0; it < BM / 64; ++it) {
        const int c = tid + 256 * it;
        const int kp = c & 15;
        const int lq = (c >> 4) * 4;
        const int mrow = m0 + lq;
        const int bb = mrow / SL;
        const size_t rowo = (size_t)(bb * K + k0 + 2 * kp) * SL + (mrow - bb * SL);
        const float4 v0 = *(const float4*)&Afp[rowo];
        const float4 v1 = *(const float4*)&Afp[rowo + SL];
        const float ve0[4] = {v0.x, v0.y, v0.z, v0.w};
        const float ve1[4] = {v1.x, v1.y, v1.z, v1.w};
#pragma unroll
        for (int e = 0; e < 4; ++e) {
          const unsigned int pk =
              (unsigned int)cvt_bf(ve0[e]) | ((unsigned int)cvt_bf(ve1[e]) << 16);
          *(unsigned int*)&As[(lq + e) * 40 + 2 * kp] = pk;
        }
      }
    } else {
#pragma unroll
      for (int it = 0; it < (BM * 4) / 256; ++it) {
        const int c = tid + 256 * it;
        const int row = c >> 2, ks = (c & 3) * 8;
        *(short8*)&As[row * 40 + ks] =
            *(const short8*)&A[(size_t)(m0 + row) * K + k0 + ks];
      }
    }
#pragma unroll
    for (int it = 0; it < (BN * 8) / 256; ++it) {
      const int c = tid + 256 * it;
      const int row = c >> 3, ks = (c & 7) * 4;
      float4 v = make_float4(0.f, 0.f, 0.f, 0.f);
      if (!NMASK || (n0 + row) < NCAP)
        v = *(const float4*)&W[(size_t)(n0 + row) * K + k0 + ks];
      short4v o4;
      o4[0] = (short)cvt_bf(v.x);
      o4[1] = (short)cvt_bf(v.y);
      o4[2] = (short)cvt_bf(v.z);
      o4[3] = (short)cvt_bf(v.w);
      *(short4v*)&Bs[row * 40 + ks] = o4;
    }
    __syncthreads();
    short8 af[FM], bfv[FN];
#pragma unroll
    for (int i = 0; i < FM; ++i)
      af[i] = *(const short8*)&As[(wm * WM + i * 16 + r16) * 40 + kg];
#pragma unroll
    for (int j = 0; j < FN; ++j)
      bfv[j] = *(const short8*)&Bs[(wn * WN + j * 16 + r16) * 40 + kg];
#pragma unroll
    for (int i = 0; i < FM; ++i)
#pragma unroll
      for (int j = 0; j < FN; ++j)
        acc[i][j] = __builtin_amdgcn_mfma_f32_16x16x32_bf16(af[i], bfv[j],
                                                            acc[i][j], 0, 0, 0);
    __syncthreads();
  }

#pragma unroll
  for (int i = 0; i < FM; ++i) {
#pragma unroll
    for (int j = 0; j < FN; ++j) {
      const int n = n0 + wn * WN + j * 16 + r16;
      const int mb = m0 + wm * WM + i * 16 + ((lane >> 4) << 2);
      f32x4 a = acc[i][j];
      if (MEPI == 0) {
        if (n < DR) {
#pragma unroll
          for (int r = 0; r < 4; ++r) out[(size_t)(mb + r) * DR + n] = a[r];
        } else if (n < NCAP) {
#pragma unroll
          for (int r = 0; r < 4; ++r) out2[(size_t)(mb + r) * 32 + (n - DR)] = a[r];
        }
      } else if (MEPI == 1) {
        float* base = out;
        int nn = n;
        if (n >= DI) { base = out2; nn = n - DI; }
        const int bb = mb / SL;
        const int ll = mb - bb * SL;
        *(f32x4*)&base[((size_t)(bb * DI + nn)) * SL + ll] = a;
      } else {  // MEPI 2
#pragma unroll
        for (int r = 0; r < 4; ++r) {
          const size_t off = (size_t)(mb + r) * DM + n;
          const float nv = out[off] + a[r];
          out[off] = nv;
          outb[off] = cvt_bf(nv);
        }
      }
    }
  }
}

// ---------------- fp32 SIMT GEMM (dt_proj, K=24) ----------------
template <int EPI, bool KTAIL, int NCAP>
__global__ __launch_bounds__(256) void k_gemm(
    const float* __restrict__ A, const float* __restrict__ W,
    const float* __restrict__ bias, float* __restrict__ out, int K, int lda) {
  __shared__ float sm[4352];
  const int tid = threadIdx.x;
  const int m0 = blockIdx.x * 64;
  const int n0 = blockIdx.y * 64;
  const int b = m0 / SL, l0 = m0 % SL;
  const int tm = tid >> 4, tn = tid & 15;
  float acc[4][4] = {};
  float* As = sm;
  float* Ws = sm + 16 * 68;

  const int nk = (K + 15) / 16;
  for (int kt = 0; kt < nk; ++kt) {
    const int k0 = kt * 16;
    {
      const int row = tid >> 2;
      const int kq = (tid & 3) * 4;
      const int kb = k0 + kq;
      float4 v = make_float4(0.f, 0.f, 0.f, 0.f);
      if (!KTAIL || kb < K) v = *(const float4*)&A[(size_t)(m0 + row) * lda + kb];
      As[(kq + 0) * 68 + row] = v.x;
      As[(kq + 1) * 68 + row] = v.y;
      As[(kq + 2) * 68 + row] = v.z;
      As[(kq + 3) * 68 + row] = v.w;
    }
    {
      const int row = tid >> 2;
      const int kq = (tid & 3) * 4;
      const int kb = k0 + kq;
      float4 v = make_float4(0.f, 0.f, 0.f, 0.f);
      const bool nok = (NCAP % 64 == 0) || (n0 + row < NCAP);
      if (nok && (!KTAIL || kb < K)) v = *(const float4*)&W[(size_t)(n0 + row) * K + kb];
      Ws[(kq + 0) * 68 + row] = v.x;
      Ws[(kq + 1) * 68 + row] = v.y;
      Ws[(kq + 2) * 68 + row] = v.z;
      Ws[(kq + 3) * 68 + row] = v.w;
    }
    __syncthreads();
#pragma unroll
    for (int kk = 0; kk < 16; ++kk) {
      const float4 av = *(const float4*)&As[kk * 68 + 4 * tm];
      const float4 wv = *(const float4*)&Ws[kk * 68 + 4 * tn];
      const float ax[4] = {av.x, av.y, av.z, av.w};
      const float wx[4] = {wv.x, wv.y, wv.z, wv.w};
#pragma unroll
      for (int i = 0; i < 4; ++i)
#pragma unroll
        for (int j = 0; j < 4; ++j) acc[i][j] = fmaf(ax[i], wx[j], acc[i][j]);
    }
    __syncthreads();
  }

#pragma unroll
  for (int j = 0; j < 4; ++j) {
    const int nn = 4 * tn + j;
#pragma unroll
    for (int i = 0; i < 4; ++i) {
      float v = acc[i][j];
      if (EPI == 2) v = softplusf(v + bias[n0 + nn]);
      sm[nn * 68 + 4 * tm + i] = v;
    }
  }
  __syncthreads();
  const int row = tid >> 2;
  const int seg = (tid & 3) * 16;
  const float* src = &sm[row * 68 + seg];
  float* dst = out + ((size_t)(b * DI + n0 + row)) * SL + l0 + seg;
#pragma unroll
  for (int q = 0; q < 4; ++q) {
    *(float4*)&dst[q * 4] = *(const float4*)&src[q * 4];
  }
}

// ---------------- depthwise causal conv1d + bias + silu (4 l per thread) --------
__global__ void k_conv(const float* __restrict__ xcT, const float* __restrict__ cw,
                       const float* __restrict__ cb, float* __restrict__ uT) {
  const size_t idx = (size_t)blockIdx.x * 256 + threadIdx.x;
  const int l4 = (int)(idx % (SL / 4)) * 4;
  const int bd = (int)(idx / (SL / 4));
  const int d = bd % DI;
  const float* row = xcT + (size_t)bd * SL;
  const float4 w = *(const float4*)&cw[d * 4];
  const float4 cur = *(const float4*)&row[l4];
  float p1 = 0.f, p2 = 0.f, p3 = 0.f;
  if (l4 > 0) {
    const float4 pv = *(const float4*)&row[l4 - 4];
    p1 = pv.y; p2 = pv.z; p3 = pv.w;
  }
  const float cbd = cb[d];
  float4 o;
  o.x = cbd + w.w * cur.x + w.z * p3 + w.y * p2 + w.x * p1;
  o.y = cbd + w.w * cur.y + w.z * cur.x + w.y * p3 + w.x * p2;
  o.z = cbd + w.w * cur.z + w.z * cur.y + w.y * cur.x + w.x * p3;
  o.w = cbd + w.w * cur.w + w.z * cur.z + w.y * cur.y + w.x * cur.x;
  o.x = siluf(o.x); o.y = siluf(o.y); o.z = siluf(o.z); o.w = siluf(o.w);
  *(float4*)&uT[(size_t)bd * SL + l4] = o;
}

// ---------------- fused hierarchical selective scan --------------------------
// 1 block per chain. 256 thr = 16 groups (g) x 16 state-lanes (n).
// Tile = 224 steps: group g owns steps [g*14, g*14+14). Pass1 keeps da/dbu in
// registers; LDS Hillis-Steele composes (A,B) across groups; pass2 = 1 fma/step.
__global__ __launch_bounds__(256) void k_scanf(
    const float* __restrict__ deltaT, const float* __restrict__ uT,
    const float* __restrict__ BC, const float* __restrict__ resT,
    const float* __restrict__ A_log, const float* __restrict__ Dp,
    float* __restrict__ yT) {
  __shared__ float As_[2][NGRP][DSN + 1];
  __shared__ float Bs_[2][NGRP][DSN + 1];
  const int tid = threadIdx.x;
  const int n = tid & 15, g = tid >> 4;
  const int chain = blockIdx.x;
  const int b = chain / DI, d = chain % DI;
  const float a2 = -expf(A_log[d * DSN + n]) * 1.44269504088896341f;
  const float dp = Dp[d];
  const float* drow = deltaT + (size_t)chain * SL;
  const float* urow = uT + (size_t)chain * SL;
  const float* resr = resT + (size_t)chain * SL;
  const float* bcb = BC + (size_t)b * SL * 32;
  float* yr = yT + (size_t)chain * SL;
  float carry = 0.f;

  for (int tb = 0; tb < SL; tb += TILE) {
    const int l0 = tb + g * KS;
    float da[KS], dbu[KS];
    float h = 0.f, dsum = 0.f;
#pragma unroll
    for (int k = 0; k < KS; ++k) {
      const float dl = drow[l0 + k];
      const float ul = urow[l0 + k];
      const float Bv = bcb[(size_t)(l0 + k) * 32 + n];
      const float e = exp2f(dl * a2);
      da[k] = e;
      dbu[k] = dl * ul * Bv;
      h = fmaf(e, h, dbu[k]);
      dsum += dl;
    }
    // local transform: h_out = A*h_in + B
    As_[0][g][n] = exp2f(a2 * dsum);
    Bs_[0][g][n] = h;
    __syncthreads();
    // inclusive Hillis-Steele over groups (4 rounds, ping-pong)
    int src = 0;
#pragma unroll
    for (int off = 1; off < NGRP; off <<= 1) {
      float Ai = As_[src][g][n], Bi = Bs_[src][g][n];
      if (g >= off) {
        const float Ae = As_[src][g - off][n];
        const float Be = Bs_[src][g - off][n];
        Bi = fmaf(Ai, Be, Bi);
        Ai *= Ae;
      }
      As_[src ^ 1][g][n] = Ai;
      Bs_[src ^ 1][g][n] = Bi;
      src ^= 1;
      __syncthreads();
    }
    // src == 0: final inclusive prefixes in buffer 0.
    float hstart;
    if (g == 0) {
      hstart = carry;
    } else {
      hstart = fmaf(As_[0][g - 1][n], carry, Bs_[0][g - 1][n]);
    }
    const float A15 = As_[0][NGRP - 1][n];
    const float B15 = Bs_[0][NGRP - 1][n];
    // pass 2: cached-coefficient recurrence + C-projection
    float p[KS];
    h = hstart;
#pragma unroll
    for (int k = 0; k < KS; ++k) {
      h = fmaf(da[k], h, dbu[k]);
      p[k] = h * bcb[(size_t)(l0 + k) * 32 + 16 + n];
    }
    carry = fmaf(A15, carry, B15);
    // reduce p over the 16 state lanes (8-wide batches of butterflies)
#pragma unroll
    for (int k = 0; k < KS; ++k) p[k] += __shfl_xor(p[k], 1);
#pragma unroll
    for (int k = 0; k < KS; ++k) p[k] += __shfl_xor(p[k], 2);
#pragma unroll
    for (int k = 0; k < KS; ++k) p[k] += __shfl_xor(p[k], 4);
#pragma unroll
    for (int k = 0; k < KS; ++k) p[k] += __shfl_xor(p[k], 8);
    float myp = p[0];
#pragma unroll
    for (int k = 1; k < KS; ++k) myp = (n == k) ? p[k] : myp;
    if (n < KS) {
      const float ul = urow[l0 + n];
      const float r = resr[l0 + n];
      yr[l0 + n] = (myp + ul * dp) * siluf(r);
    }
    __syncthreads();  // protect LDS buf0 before next tile's writes
  }
}

// ---------------- RMS denom ----------------
__global__ void k_rinv(const float* __restrict__ t, float* __restrict__ rinv) {
  const int row = blockIdx.x;
  const float* tr = t + (size_t)row * DM;
  const int tid = threadIdx.x;
  float ss = 0.f;
#pragma unroll
  for (int k = 0; k < DM / 64; ++k) {
    const float v = tr[tid + k * 64];
    ss = fmaf(v, v, ss);
  }
  ss += __shfl_xor(ss, 1);
  ss += __shfl_xor(ss, 2);
  ss += __shfl_xor(ss, 4);
  ss += __shfl_xor(ss, 8);
  ss += __shfl_xor(ss, 16);
  ss += __shfl_xor(ss, 32);
  if (tid == 0) rinv[row] = 1.f / sqrtf(ss / DM + 1e-5f);
}

// ---------------- pooled partial sums ----------------
__global__ void k_pool(const float* __restrict__ t, const float* __restrict__ rinv,
                       float* __restrict__ part) {
  const int b = blockIdx.x, dmb = blockIdx.y, ch = blockIdx.z;
  const int dm = dmb * 64 + threadIdx.x;
  const int lbeg = ch * (SL / 32);
  float s = 0.f;
  for (int l = lbeg; l < lbeg + SL / 32; ++l)
    s = fmaf(t[((size_t)b * SL + l) * DM + dm], rinv[b * SL + l], s);
  part[((size_t)ch * NB + b) * DM + dm] = s;
}

// ---------------- head ----------------
__global__ void k_head(const float* __restrict__ part, const float* __restrict__ norm_w,
                       const float* __restrict__ hw, const float* __restrict__ hb,
                       float* __restrict__ out) {
  const int b = blockIdx.x;
  const int tid = threadIdx.x;
  __shared__ float pv[DM];
  for (int k = tid; k < DM; k += 64) {
    float s = 0.f;
#pragma unroll
    for (int c = 0; c < 32; ++c) s += part[((size_t)c * NB + b) * DM + k];
    pv[k] = s * norm_w[k] * (1.f / SL);
  }
  __syncthreads();
  const int cls = blockIdx.y * 64 + tid;
  if (cls < NCLS) {
    const float* wr = hw + (size_t)cls * DM;
    float acc = hb[cls];
#pragma unroll 4
    for (int k = 0; k < DM; k += 4) {
      const float4 w4 = *(const float4*)&wr[k];
      acc = fmaf(pv[k], w4.x, acc);
      acc = fmaf(pv[k + 1], w4.y, acc);
      acc = fmaf(pv[k + 2], w4.z, acc);
      acc = fmaf(pv[k + 3], w4.w, acc);
    }
    out[(size_t)b * NCLS + cls] = acc;
  }
}

extern "C" void kernel_launch(void* const* d_in, const int* in_sizes, int n_in,
                              void* d_out, int out_size, void* d_ws, size_t ws_size,
                              hipStream_t stream) {
  (void)in_sizes; (void)n_in; (void)out_size; (void)ws_size;
  const float* x = (const float*)d_in[0];
  const float* patch_w = (const float*)d_in[1];
  const float* patch_b = (const float*)d_in[2];
  const float* in_proj_w = (const float*)d_in[3];
  const float* conv_w = (const float*)d_in[4];
  const float* conv_b = (const float*)d_in[5];
  const float* x_proj_w = (const float*)d_in[6];
  const float* dt_proj_w = (const float*)d_in[7];
  const float* dt_proj_b = (const float*)d_in[8];
  const float* A_log = (const float*)d_in[9];
  const float* Dp = (const float*)d_in[10];
  const float* out_proj_w = (const float*)d_in[11];
  const float* norm_w = (const float*)d_in[12];
  const float* head_w = (const float*)d_in[13];
  const float* head_b = (const float*)d_in[14];

  float* ws = (float*)d_ws;
  size_t o = 0;
  float* t = ws + o;     o += (size_t)NB * SL * DM;
  float* xcT = ws + o;   o += (size_t)NB * DI * SL;
  float* resT = ws + o;  o += (size_t)NB * DI * SL;
  float* uT = ws + o;    o += (size_t)NB * DI * SL;
  float* dltT = ws + o;  o += (size_t)NB * DI * SL;
  float* yT = ws + o;    o += (size_t)NB * DI * SL;
  float* dbl24 = ws + o; o += (size_t)NB * SL * DR;
  float* BC = ws + o;    o += (size_t)NB * SL * 32;
  float* rinv = ws + o;  o += (size_t)NB * SL;
  float* part = ws + o;  o += (size_t)32 * NB * DM;
  unsigned short* tb = (unsigned short*)(ws + o); o += (size_t)NB * SL * DM / 2;

  k_patch<<<NB * SL, 128, 0, stream>>>(x, patch_w, patch_b, t, tb);

  for (int i = 0; i < NLAYER; ++i) {
    // in_proj: tb[M,384](bf16) x W[1536,384]^T -> xcT / resT ([b][n][l] fp32)
    k_mgemm<128, 128, 1, 1536, false><<<dim3(98, 12), 256, 0, stream>>>(
        tb, nullptr, in_proj_w + (size_t)i * 2 * DI * DM, xcT, resT, nullptr, DM);
    // depthwise causal conv + silu -> uT
    k_conv<<<(NB * DI * SL / 4) / 256, 256, 0, stream>>>(
        xcT, conv_w + (size_t)i * DI * 4, conv_b + (size_t)i * DI, uT);
    // x_proj: uT (AT-staged bf16) x W[56,768]^T -> dbl24 + BC[b][l][32]
    k_mgemm<64, 64, 0, XPN, true><<<dim3(196, 1), 256, 0, stream>>>(
        nullptr, uT, x_proj_w + (size_t)i * XPN * DI, dbl24, BC, nullptr, DI);
    // dt_proj (fp32 SIMT): softplus(dbl24 @ dt_w^T + b) -> dltT [b][d][l]
    k_gemm<2, true, 64><<<dim3(196, 12), 256, 0, stream>>>(
        dbl24, dt_proj_w + (size_t)i * DI * DR, dt_proj_b + (size_t)i * DI, dltT,
        DR, DR);
    // fused hierarchical selective scan + gate -> yT
    k_scanf<<<NCHAIN, 256, 0, stream>>>(
        dltT, uT, BC, resT, A_log + (size_t)i * DI * DSN, Dp + (size_t)i * DI, yT);
    // out_proj: yT (AT-staged bf16) x W[384,768]^T -> t += ; tb = bf16(t)
    k_mgemm<128, 128, 2, 384, true><<<dim3(98, 3), 256, 0, stream>>>(
        nullptr, yT, out_proj_w + (size_t)i * DM * DI, t, nullptr, tb, DI);
  }

  k_rinv<<<NB * SL, 64, 0, stream>>>(t, rinv);
  k_pool<<<dim3(NB, DM / 64, 32), 64, 0, stream>>>(t, rinv, part);
  k_head<<<dim3(NB, 16), 64, 0, stream>>>(part, norm_w, head_w, head_b, (float*)d_out);
}

// Round 8
// 1428.987 us; speedup vs baseline: 1.5608x; 1.0632x over previous
//
#include <hip/hip_runtime.h>
#include <math.h>

// CausalVisionMamba — round 8: wave-synchronous fused scan (k_scanw):
// 1 wave per chain, shuffle-based group compose, no LDS, no barriers.

namespace {
constexpr int NB = 4;
constexpr int SL = 3136;
constexpr int DM = 384;
constexpr int DI = 768;
constexpr int DSN = 16;
constexpr int DR = 24;
constexpr int NLAYER = 4;
constexpr int NCLS = 1000;
constexpr int XPN = DR + 2 * DSN;  // 56
constexpr int NCHAIN = NB * DI;    // 3072
}

typedef float f32x4 __attribute__((ext_vector_type(4)));
typedef short short8 __attribute__((ext_vector_type(8)));
typedef short short4v __attribute__((ext_vector_type(4)));

__device__ __forceinline__ float siluf(float x) { return x / (1.f + expf(-x)); }
__device__ __forceinline__ float softplusf(float x) {
  return fmaxf(x, 0.f) + log1pf(expf(-fabsf(x)));
}
__device__ __forceinline__ unsigned short cvt_bf(float f) {
  unsigned int x = __float_as_uint(f);
  unsigned int r = (x + 0x7fffu + ((x >> 16) & 1u)) >> 16;  // RNE
  return (unsigned short)r;
}

// ---------------- patch embed: t[b][l][dm] fp32 + tb bf16 ----------------
__global__ void k_patch(const float* __restrict__ x, const float* __restrict__ w,
                        const float* __restrict__ bias, float* __restrict__ t,
                        unsigned short* __restrict__ tb) {
  const int blk = blockIdx.x;
  const int b = blk / SL, l = blk % SL;
  const int hh = l / 56, ww = l % 56;
  __shared__ float patch[48];
  const int tid = threadIdx.x;
  if (tid < 48) {
    const int c = tid / 16, kh = (tid % 16) / 4, kw = tid % 4;
    patch[tid] = x[((size_t)(b * 3 + c) * 224 + (hh * 4 + kh)) * 224 + (ww * 4 + kw)];
  }
  __syncthreads();
  for (int dm = tid; dm < DM; dm += 128) {
    const float* wr = w + (size_t)dm * 48;
    float acc = bias[dm];
#pragma unroll
    for (int p = 0; p < 48; ++p) acc = fmaf(patch[p], wr[p], acc);
    const size_t o = ((size_t)b * SL + l) * DM + dm;
    t[o] = acc;
    tb[o] = cvt_bf(acc);
  }
}

// ---------------- bf16 MFMA GEMM: D = A[M,K](bf16) * W[N,K]^T(fp32->bf16) -------
template <int BM, int BN, int MEPI, int NCAP, bool AT>
__global__ __launch_bounds__(256) void k_mgemm(
    const unsigned short* __restrict__ A, const float* __restrict__ Afp,
    const float* __restrict__ W, float* __restrict__ out,
    float* __restrict__ out2, unsigned short* __restrict__ outb, const int K) {
  constexpr int WM = BM / 2, WN = BN / 2, FM = WM / 16, FN = WN / 16;
  constexpr bool NMASK = (NCAP % BN) != 0;
  __shared__ unsigned short As[BM * 40];
  __shared__ unsigned short Bs[BN * 40];
  const int tid = threadIdx.x;
  const int lane = tid & 63, wave = tid >> 6;
  const int wm = wave >> 1, wn = wave & 1;
  const int m0 = blockIdx.x * BM, n0 = blockIdx.y * BN;
  const int r16 = lane & 15, kg = (lane >> 4) * 8;
  f32x4 acc[FM][FN] = {};
  const int nk = K >> 5;
  for (int kt = 0; kt < nk; ++kt) {
    const int k0 = kt << 5;
    if constexpr (AT) {
#pragma unroll
      for (int it = 0; it < BM / 64; ++it) {
        const int c = tid + 256 * it;
        const int kp = c & 15;
        const int lq = (c >> 4) * 4;
        const int mrow = m0 + lq;
        const int bb = mrow / SL;
        const size_t rowo = (size_t)(bb * K + k0 + 2 * kp) * SL + (mrow - bb * SL);
        const float4 v0 = *(const float4*)&Afp[rowo];
        const float4 v1 = *(const float4*)&Afp[rowo + SL];
        const float ve0[4] = {v0.x, v0.y, v0.z, v0.w};
        const float ve1[4] = {v1.x, v1.y, v1.z, v1.w};
#pragma unroll
        for (int e = 0; e < 4; ++e) {
          const unsigned int pk =
              (unsigned int)cvt_bf(ve0[e]) | ((unsigned int)cvt_bf(ve1[e]) << 16);
          *(unsigned int*)&As[(lq + e) * 40 + 2 * kp] = pk;
        }
      }
    } else {
#pragma unroll
      for (int it = 0; it < (BM * 4) / 256; ++it) {
        const int c = tid + 256 * it;
        const int row = c >> 2, ks = (c & 3) * 8;
        *(short8*)&As[row * 40 + ks] =
            *(const short8*)&A[(size_t)(m0 + row) * K + k0 + ks];
      }
    }
#pragma unroll
    for (int it = 0; it < (BN * 8) / 256; ++it) {
      const int c = tid + 256 * it;
      const int row = c >> 3, ks = (c & 7) * 4;
      float4 v = make_float4(0.f, 0.f, 0.f, 0.f);
      if (!NMASK || (n0 + row) < NCAP)
        v = *(const float4*)&W[(size_t)(n0 + row) * K + k0 + ks];
      short4v o4;
      o4[0] = (short)cvt_bf(v.x);
      o4[1] = (short)cvt_bf(v.y);
      o4[2] = (short)cvt_bf(v.z);
      o4[3] = (short)cvt_bf(v.w);
      *(short4v*)&Bs[row * 40 + ks] = o4;
    }
    __syncthreads();
    short8 af[FM], bfv[FN];
#pragma unroll
    for (int i = 0; i < FM; ++i)
      af[i] = *(const short8*)&As[(wm * WM + i * 16 + r16) * 40 + kg];
#pragma unroll
    for (int j = 0; j < FN; ++j)
      bfv[j] = *(const short8*)&Bs[(wn * WN + j * 16 + r16) * 40 + kg];
#pragma unroll
    for (int i = 0; i < FM; ++i)
#pragma unroll
      for (int j = 0; j < FN; ++j)
        acc[i][j] = __builtin_amdgcn_mfma_f32_16x16x32_bf16(af[i], bfv[j],
                                                            acc[i][j], 0, 0, 0);
    __syncthreads();
  }

#pragma unroll
  for (int i = 0; i < FM; ++i) {
#pragma unroll
    for (int j = 0; j < FN; ++j) {
      const int n = n0 + wn * WN + j * 16 + r16;
      const int mb = m0 + wm * WM + i * 16 + ((lane >> 4) << 2);
      f32x4 a = acc[i][j];
      if (MEPI == 0) {
        if (n < DR) {
#pragma unroll
          for (int r = 0; r < 4; ++r) out[(size_t)(mb + r) * DR + n] = a[r];
        } else if (n < NCAP) {
#pragma unroll
          for (int r = 0; r < 4; ++r) out2[(size_t)(mb + r) * 32 + (n - DR)] = a[r];
        }
      } else if (MEPI == 1) {
        float* base = out;
        int nn = n;
        if (n >= DI) { base = out2; nn = n - DI; }
        const int bb = mb / SL;
        const int ll = mb - bb * SL;
        *(f32x4*)&base[((size_t)(bb * DI + nn)) * SL + ll] = a;
      } else {  // MEPI 2
#pragma unroll
        for (int r = 0; r < 4; ++r) {
          const size_t off = (size_t)(mb + r) * DM + n;
          const float nv = out[off] + a[r];
          out[off] = nv;
          outb[off] = cvt_bf(nv);
        }
      }
    }
  }
}

// ---------------- fp32 SIMT GEMM (dt_proj, K=24) ----------------
template <int EPI, bool KTAIL, int NCAP>
__global__ __launch_bounds__(256) void k_gemm(
    const float* __restrict__ A, const float* __restrict__ W,
    const float* __restrict__ bias, float* __restrict__ out, int K, int lda) {
  __shared__ float sm[4352];
  const int tid = threadIdx.x;
  const int m0 = blockIdx.x * 64;
  const int n0 = blockIdx.y * 64;
  const int b = m0 / SL, l0 = m0 % SL;
  const int tm = tid >> 4, tn = tid & 15;
  float acc[4][4] = {};
  float* As = sm;
  float* Ws = sm + 16 * 68;

  const int nk = (K + 15) / 16;
  for (int kt = 0; kt < nk; ++kt) {
    const int k0 = kt * 16;
    {
      const int row = tid >> 2;
      const int kq = (tid & 3) * 4;
      const int kb = k0 + kq;
      float4 v = make_float4(0.f, 0.f, 0.f, 0.f);
      if (!KTAIL || kb < K) v = *(const float4*)&A[(size_t)(m0 + row) * lda + kb];
      As[(kq + 0) * 68 + row] = v.x;
      As[(kq + 1) * 68 + row] = v.y;
      As[(kq + 2) * 68 + row] = v.z;
      As[(kq + 3) * 68 + row] = v.w;
    }
    {
      const int row = tid >> 2;
      const int kq = (tid & 3) * 4;
      const int kb = k0 + kq;
      float4 v = make_float4(0.f, 0.f, 0.f, 0.f);
      const bool nok = (NCAP % 64 == 0) || (n0 + row < NCAP);
      if (nok && (!KTAIL || kb < K)) v = *(const float4*)&W[(size_t)(n0 + row) * K + kb];
      Ws[(kq + 0) * 68 + row] = v.x;
      Ws[(kq + 1) * 68 + row] = v.y;
      Ws[(kq + 2) * 68 + row] = v.z;
      Ws[(kq + 3) * 68 + row] = v.w;
    }
    __syncthreads();
#pragma unroll
    for (int kk = 0; kk < 16; ++kk) {
      const float4 av = *(const float4*)&As[kk * 68 + 4 * tm];
      const float4 wv = *(const float4*)&Ws[kk * 68 + 4 * tn];
      const float ax[4] = {av.x, av.y, av.z, av.w};
      const float wx[4] = {wv.x, wv.y, wv.z, wv.w};
#pragma unroll
      for (int i = 0; i < 4; ++i)
#pragma unroll
        for (int j = 0; j < 4; ++j) acc[i][j] = fmaf(ax[i], wx[j], acc[i][j]);
    }
    __syncthreads();
  }

#pragma unroll
  for (int j = 0; j < 4; ++j) {
    const int nn = 4 * tn + j;
#pragma unroll
    for (int i = 0; i < 4; ++i) {
      float v = acc[i][j];
      if (EPI == 2) v = softplusf(v + bias[n0 + nn]);
      sm[nn * 68 + 4 * tm + i] = v;
    }
  }
  __syncthreads();
  const int row = tid >> 2;
  const int seg = (tid & 3) * 16;
  const float* src = &sm[row * 68 + seg];
  float* dst = out + ((size_t)(b * DI + n0 + row)) * SL + l0 + seg;
#pragma unroll
  for (int q = 0; q < 4; ++q) {
    *(float4*)&dst[q * 4] = *(const float4*)&src[q * 4];
  }
}

// ---------------- depthwise causal conv1d + bias + silu (4 l per thread) --------
__global__ void k_conv(const float* __restrict__ xcT, const float* __restrict__ cw,
                       const float* __restrict__ cb, float* __restrict__ uT) {
  const size_t idx = (size_t)blockIdx.x * 256 + threadIdx.x;
  const int l4 = (int)(idx % (SL / 4)) * 4;
  const int bd = (int)(idx / (SL / 4));
  const int d = bd % DI;
  const float* row = xcT + (size_t)bd * SL;
  const float4 w = *(const float4*)&cw[d * 4];
  const float4 cur = *(const float4*)&row[l4];
  float p1 = 0.f, p2 = 0.f, p3 = 0.f;
  if (l4 > 0) {
    const float4 pv = *(const float4*)&row[l4 - 4];
    p1 = pv.y; p2 = pv.z; p3 = pv.w;
  }
  const float cbd = cb[d];
  float4 o;
  o.x = cbd + w.w * cur.x + w.z * p3 + w.y * p2 + w.x * p1;
  o.y = cbd + w.w * cur.y + w.z * cur.x + w.y * p3 + w.x * p2;
  o.z = cbd + w.w * cur.z + w.z * cur.y + w.y * cur.x + w.x * p3;
  o.w = cbd + w.w * cur.w + w.z * cur.z + w.y * cur.y + w.x * cur.x;
  o.x = siluf(o.x); o.y = siluf(o.y); o.z = siluf(o.z); o.w = siluf(o.w);
  *(float4*)&uT[(size_t)bd * SL + l4] = o;
}

// ---------------- wave-synchronous fused selective scan -----------------------
// 1 wave per chain (4 chains / 256-block). lane = g*16+n: 4 step-groups x 16 n.
// Tile = 64 steps; pass1 caches da/dbu in regs; 2-round shuffle Hillis-Steele
// composes group transforms; pass2 = 1 fma/step + C-mul; butterfly reduce.
__global__ __launch_bounds__(256) void k_scanw(
    const float* __restrict__ deltaT, const float* __restrict__ uT,
    const float* __restrict__ BC, const float* __restrict__ resT,
    const float* __restrict__ A_log, const float* __restrict__ Dp,
    float* __restrict__ yT) {
  const int tid = threadIdx.x;
  const int lane = tid & 63, wv = tid >> 6;
  const int n = lane & 15, g = lane >> 4;
  const int chain = blockIdx.x * 4 + wv;
  const int b = chain / DI, d = chain % DI;
  const float a2 = -expf(A_log[d * DSN + n]) * 1.44269504088896341f;
  const float dp = Dp[d];
  const float* drow = deltaT + (size_t)chain * SL;
  const float* urow = uT + (size_t)chain * SL;
  const float* resr = resT + (size_t)chain * SL;
  const float* bcb = BC + (size_t)b * SL * 32;
  float* yr = yT + (size_t)chain * SL;
  float carry = 0.f;

  for (int tb = 0; tb < SL; tb += 64) {
    const int l0 = tb + g * 16;
    float da[16], dbu[16];
    float h = 0.f, dsum = 0.f;
#pragma unroll
    for (int k = 0; k < 16; ++k) {
      const float dl = drow[l0 + k];
      const float ul = urow[l0 + k];
      const float Bv = bcb[(size_t)(l0 + k) * 32 + n];
      const float e = exp2f(dl * a2);
      da[k] = e;
      dbu[k] = dl * ul * Bv;
      h = fmaf(e, h, dbu[k]);
      dsum += dl;
    }
    // group transform: h_out = Aagg*h_in + Bagg
    float Aagg = exp2f(a2 * dsum);
    float Bagg = h;
    // inclusive Hillis-Steele over the 4 groups (lane offsets 16, 32)
#pragma unroll
    for (int off = 16; off <= 32; off <<= 1) {
      const float Ae = __shfl(Aagg, (lane - off) & 63);
      const float Be = __shfl(Bagg, (lane - off) & 63);
      if (lane >= off) {
        Bagg = fmaf(Aagg, Be, Bagg);
        Aagg *= Ae;
      }
    }
    // exclusive prefix (from g-1) applied to carry
    const float Pa = __shfl(Aagg, (lane - 16) & 63);
    const float Pb = __shfl(Bagg, (lane - 16) & 63);
    const float hstart = (g == 0) ? carry : fmaf(Pa, carry, Pb);
    // whole-tile transform from g=3 (same n)
    const float cA = __shfl(Aagg, 48 | n);
    const float cB = __shfl(Bagg, 48 | n);
    // pass 2: cached-coefficient recurrence + C projection
    float p[16];
    h = hstart;
#pragma unroll
    for (int k = 0; k < 16; ++k) {
      h = fmaf(da[k], h, dbu[k]);
      p[k] = h * bcb[(size_t)(l0 + k) * 32 + 16 + n];
    }
    carry = fmaf(cA, carry, cB);
    // butterfly reduce over the 16 state lanes
#pragma unroll
    for (int k = 0; k < 16; ++k) p[k] += __shfl_xor(p[k], 1);
#pragma unroll
    for (int k = 0; k < 16; ++k) p[k] += __shfl_xor(p[k], 2);
#pragma unroll
    for (int k = 0; k < 16; ++k) p[k] += __shfl_xor(p[k], 4);
#pragma unroll
    for (int k = 0; k < 16; ++k) p[k] += __shfl_xor(p[k], 8);
    float myp = p[0];
#pragma unroll
    for (int k = 1; k < 16; ++k) myp = (n == k) ? p[k] : myp;
    const float ul = urow[l0 + n];
    const float r = resr[l0 + n];
    yr[l0 + n] = (myp + ul * dp) * siluf(r);
  }
}

// ---------------- RMS denom ----------------
__global__ void k_rinv(const float* __restrict__ t, float* __restrict__ rinv) {
  const int row = blockIdx.x;
  const float* tr = t + (size_t)row * DM;
  const int tid = threadIdx.x;
  float ss = 0.f;
#pragma unroll
  for (int k = 0; k < DM / 64; ++k) {
    const float v = tr[tid + k * 64];
    ss = fmaf(v, v, ss);
  }
  ss += __shfl_xor(ss, 1);
  ss += __shfl_xor(ss, 2);
  ss += __shfl_xor(ss, 4);
  ss += __shfl_xor(ss, 8);
  ss += __shfl_xor(ss, 16);
  ss += __shfl_xor(ss, 32);
  if (tid == 0) rinv[row] = 1.f / sqrtf(ss / DM + 1e-5f);
}

// ---------------- pooled partial sums ----------------
__global__ void k_pool(const float* __restrict__ t, const float* __restrict__ rinv,
                       float* __restrict__ part) {
  const int b = blockIdx.x, dmb = blockIdx.y, ch = blockIdx.z;
  const int dm = dmb * 64 + threadIdx.x;
  const int lbeg = ch * (SL / 32);
  float s = 0.f;
  for (int l = lbeg; l < lbeg + SL / 32; ++l)
    s = fmaf(t[((size_t)b * SL + l) * DM + dm], rinv[b * SL + l], s);
  part[((size_t)ch * NB + b) * DM + dm] = s;
}

// ---------------- head ----------------
__global__ void k_head(const float* __restrict__ part, const float* __restrict__ norm_w,
                       const float* __restrict__ hw, const float* __restrict__ hb,
                       float* __restrict__ out) {
  const int b = blockIdx.x;
  const int tid = threadIdx.x;
  __shared__ float pv[DM];
  for (int k = tid; k < DM; k += 64) {
    float s = 0.f;
#pragma unroll
    for (int c = 0; c < 32; ++c) s += part[((size_t)c * NB + b) * DM + k];
    pv[k] = s * norm_w[k] * (1.f / SL);
  }
  __syncthreads();
  const int cls = blockIdx.y * 64 + tid;
  if (cls < NCLS) {
    const float* wr = hw + (size_t)cls * DM;
    float acc = hb[cls];
#pragma unroll 4
    for (int k = 0; k < DM; k += 4) {
      const float4 w4 = *(const float4*)&wr[k];
      acc = fmaf(pv[k], w4.x, acc);
      acc = fmaf(pv[k + 1], w4.y, acc);
      acc = fmaf(pv[k + 2], w4.z, acc);
      acc = fmaf(pv[k + 3], w4.w, acc);
    }
    out[(size_t)b * NCLS + cls] = acc;
  }
}

extern "C" void kernel_launch(void* const* d_in, const int* in_sizes, int n_in,
                              void* d_out, int out_size, void* d_ws, size_t ws_size,
                              hipStream_t stream) {
  (void)in_sizes; (void)n_in; (void)out_size; (void)ws_size;
  const float* x = (const float*)d_in[0];
  const float* patch_w = (const float*)d_in[1];
  const float* patch_b = (const float*)d_in[2];
  const float* in_proj_w = (const float*)d_in[3];
  const float* conv_w = (const float*)d_in[4];
  const float* conv_b = (const float*)d_in[5];
  const float* x_proj_w = (const float*)d_in[6];
  const float* dt_proj_w = (const float*)d_in[7];
  const float* dt_proj_b = (const float*)d_in[8];
  const float* A_log = (const float*)d_in[9];
  const float* Dp = (const float*)d_in[10];
  const float* out_proj_w = (const float*)d_in[11];
  const float* norm_w = (const float*)d_in[12];
  const float* head_w = (const float*)d_in[13];
  const float* head_b = (const float*)d_in[14];

  float* ws = (float*)d_ws;
  size_t o = 0;
  float* t = ws + o;     o += (size_t)NB * SL * DM;
  float* xcT = ws + o;   o += (size_t)NB * DI * SL;
  float* resT = ws + o;  o += (size_t)NB * DI * SL;
  float* uT = ws + o;    o += (size_t)NB * DI * SL;
  float* dltT = ws + o;  o += (size_t)NB * DI * SL;
  float* yT = ws + o;    o += (size_t)NB * DI * SL;
  float* dbl24 = ws + o; o += (size_t)NB * SL * DR;
  float* BC = ws + o;    o += (size_t)NB * SL * 32;
  float* rinv = ws + o;  o += (size_t)NB * SL;
  float* part = ws + o;  o += (size_t)32 * NB * DM;
  unsigned short* tb = (unsigned short*)(ws + o); o += (size_t)NB * SL * DM / 2;

  k_patch<<<NB * SL, 128, 0, stream>>>(x, patch_w, patch_b, t, tb);

  for (int i = 0; i < NLAYER; ++i) {
    // in_proj: tb[M,384](bf16) x W[1536,384]^T -> xcT / resT ([b][n][l] fp32)
    k_mgemm<128, 128, 1, 1536, false><<<dim3(98, 12), 256, 0, stream>>>(
        tb, nullptr, in_proj_w + (size_t)i * 2 * DI * DM, xcT, resT, nullptr, DM);
    // depthwise causal conv + silu -> uT
    k_conv<<<(NB * DI * SL / 4) / 256, 256, 0, stream>>>(
        xcT, conv_w + (size_t)i * DI * 4, conv_b + (size_t)i * DI, uT);
    // x_proj: uT (AT-staged bf16) x W[56,768]^T -> dbl24 + BC[b][l][32]
    k_mgemm<64, 64, 0, XPN, true><<<dim3(196, 1), 256, 0, stream>>>(
        nullptr, uT, x_proj_w + (size_t)i * XPN * DI, dbl24, BC, nullptr, DI);
    // dt_proj (fp32 SIMT): softplus(dbl24 @ dt_w^T + b) -> dltT [b][d][l]
    k_gemm<2, true, 64><<<dim3(196, 12), 256, 0, stream>>>(
        dbl24, dt_proj_w + (size_t)i * DI * DR, dt_proj_b + (size_t)i * DI, dltT,
        DR, DR);
    // wave-synchronous fused selective scan + gate -> yT
    k_scanw<<<NCHAIN / 4, 256, 0, stream>>>(
        dltT, uT, BC, resT, A_log + (size_t)i * DI * DSN, Dp + (size_t)i * DI, yT);
    // out_proj: yT (AT-staged bf16) x W[384,768]^T -> t += ; tb = bf16(t)
    k_mgemm<128, 128, 2, 384, true><<<dim3(98, 3), 256, 0, stream>>>(
        nullptr, yT, out_proj_w + (size_t)i * DM * DI, t, nullptr, tb, DI);
  }

  k_rinv<<<NB * SL, 64, 0, stream>>>(t, rinv);
  k_pool<<<dim3(NB, DM / 64, 32), 64, 0, stream>>>(t, rinv, part);
  k_head<<<dim3(NB, 16), 64, 0, stream>>>(part, norm_w, head_w, head_b, (float*)d_out);
}

// Round 9
// 1263.971 us; speedup vs baseline: 1.7646x; 1.1306x over previous
//
#include <hip/hip_runtime.h>
#include <math.h>

// CausalVisionMamba — round 9: k_scanw with stream-merging reduction
// (15 shuffles instead of 64 per 64-step tile).

namespace {
constexpr int NB = 4;
constexpr int SL = 3136;
constexpr int DM = 384;
constexpr int DI = 768;
constexpr int DSN = 16;
constexpr int DR = 24;
constexpr int NLAYER = 4;
constexpr int NCLS = 1000;
constexpr int XPN = DR + 2 * DSN;  // 56
constexpr int NCHAIN = NB * DI;    // 3072
}

typedef float f32x4 __attribute__((ext_vector_type(4)));
typedef short short8 __attribute__((ext_vector_type(8)));
typedef short short4v __attribute__((ext_vector_type(4)));

__device__ __forceinline__ float siluf(float x) { return x / (1.f + expf(-x)); }
__device__ __forceinline__ float softplusf(float x) {
  return fmaxf(x, 0.f) + log1pf(expf(-fabsf(x)));
}
__device__ __forceinline__ unsigned short cvt_bf(float f) {
  unsigned int x = __float_as_uint(f);
  unsigned int r = (x + 0x7fffu + ((x >> 16) & 1u)) >> 16;  // RNE
  return (unsigned short)r;
}

// ---------------- patch embed: t[b][l][dm] fp32 + tb bf16 ----------------
__global__ void k_patch(const float* __restrict__ x, const float* __restrict__ w,
                        const float* __restrict__ bias, float* __restrict__ t,
                        unsigned short* __restrict__ tb) {
  const int blk = blockIdx.x;
  const int b = blk / SL, l = blk % SL;
  const int hh = l / 56, ww = l % 56;
  __shared__ float patch[48];
  const int tid = threadIdx.x;
  if (tid < 48) {
    const int c = tid / 16, kh = (tid % 16) / 4, kw = tid % 4;
    patch[tid] = x[((size_t)(b * 3 + c) * 224 + (hh * 4 + kh)) * 224 + (ww * 4 + kw)];
  }
  __syncthreads();
  for (int dm = tid; dm < DM; dm += 128) {
    const float* wr = w + (size_t)dm * 48;
    float acc = bias[dm];
#pragma unroll
    for (int p = 0; p < 48; ++p) acc = fmaf(patch[p], wr[p], acc);
    const size_t o = ((size_t)b * SL + l) * DM + dm;
    t[o] = acc;
    tb[o] = cvt_bf(acc);
  }
}

// ---------------- bf16 MFMA GEMM: D = A[M,K](bf16) * W[N,K]^T(fp32->bf16) -------
template <int BM, int BN, int MEPI, int NCAP, bool AT>
__global__ __launch_bounds__(256) void k_mgemm(
    const unsigned short* __restrict__ A, const float* __restrict__ Afp,
    const float* __restrict__ W, float* __restrict__ out,
    float* __restrict__ out2, unsigned short* __restrict__ outb, const int K) {
  constexpr int WM = BM / 2, WN = BN / 2, FM = WM / 16, FN = WN / 16;
  constexpr bool NMASK = (NCAP % BN) != 0;
  __shared__ unsigned short As[BM * 40];
  __shared__ unsigned short Bs[BN * 40];
  const int tid = threadIdx.x;
  const int lane = tid & 63, wave = tid >> 6;
  const int wm = wave >> 1, wn = wave & 1;
  const int m0 = blockIdx.x * BM, n0 = blockIdx.y * BN;
  const int r16 = lane & 15, kg = (lane >> 4) * 8;
  f32x4 acc[FM][FN] = {};
  const int nk = K >> 5;
  for (int kt = 0; kt < nk; ++kt) {
    const int k0 = kt << 5;
    if constexpr (AT) {
#pragma unroll
      for (int it = 0; it < BM / 64; ++it) {
        const int c = tid + 256 * it;
        const int kp = c & 15;
        const int lq = (c >> 4) * 4;
        const int mrow = m0 + lq;
        const int bb = mrow / SL;
        const size_t rowo = (size_t)(bb * K + k0 + 2 * kp) * SL + (mrow - bb * SL);
        const float4 v0 = *(const float4*)&Afp[rowo];
        const float4 v1 = *(const float4*)&Afp[rowo + SL];
        const float ve0[4] = {v0.x, v0.y, v0.z, v0.w};
        const float ve1[4] = {v1.x, v1.y, v1.z, v1.w};
#pragma unroll
        for (int e = 0; e < 4; ++e) {
          const unsigned int pk =
              (unsigned int)cvt_bf(ve0[e]) | ((unsigned int)cvt_bf(ve1[e]) << 16);
          *(unsigned int*)&As[(lq + e) * 40 + 2 * kp] = pk;
        }
      }
    } else {
#pragma unroll
      for (int it = 0; it < (BM * 4) / 256; ++it) {
        const int c = tid + 256 * it;
        const int row = c >> 2, ks = (c & 3) * 8;
        *(short8*)&As[row * 40 + ks] =
            *(const short8*)&A[(size_t)(m0 + row) * K + k0 + ks];
      }
    }
#pragma unroll
    for (int it = 0; it < (BN * 8) / 256; ++it) {
      const int c = tid + 256 * it;
      const int row = c >> 3, ks = (c & 7) * 4;
      float4 v = make_float4(0.f, 0.f, 0.f, 0.f);
      if (!NMASK || (n0 + row) < NCAP)
        v = *(const float4*)&W[(size_t)(n0 + row) * K + k0 + ks];
      short4v o4;
      o4[0] = (short)cvt_bf(v.x);
      o4[1] = (short)cvt_bf(v.y);
      o4[2] = (short)cvt_bf(v.z);
      o4[3] = (short)cvt_bf(v.w);
      *(short4v*)&Bs[row * 40 + ks] = o4;
    }
    __syncthreads();
    short8 af[FM], bfv[FN];
#pragma unroll
    for (int i = 0; i < FM; ++i)
      af[i] = *(const short8*)&As[(wm * WM + i * 16 + r16) * 40 + kg];
#pragma unroll
    for (int j = 0; j < FN; ++j)
      bfv[j] = *(const short8*)&Bs[(wn * WN + j * 16 + r16) * 40 + kg];
#pragma unroll
    for (int i = 0; i < FM; ++i)
#pragma unroll
      for (int j = 0; j < FN; ++j)
        acc[i][j] = __builtin_amdgcn_mfma_f32_16x16x32_bf16(af[i], bfv[j],
                                                            acc[i][j], 0, 0, 0);
    __syncthreads();
  }

#pragma unroll
  for (int i = 0; i < FM; ++i) {
#pragma unroll
    for (int j = 0; j < FN; ++j) {
      const int n = n0 + wn * WN + j * 16 + r16;
      const int mb = m0 + wm * WM + i * 16 + ((lane >> 4) << 2);
      f32x4 a = acc[i][j];
      if (MEPI == 0) {
        if (n < DR) {
#pragma unroll
          for (int r = 0; r < 4; ++r) out[(size_t)(mb + r) * DR + n] = a[r];
        } else if (n < NCAP) {
#pragma unroll
          for (int r = 0; r < 4; ++r) out2[(size_t)(mb + r) * 32 + (n - DR)] = a[r];
        }
      } else if (MEPI == 1) {
        float* base = out;
        int nn = n;
        if (n >= DI) { base = out2; nn = n - DI; }
        const int bb = mb / SL;
        const int ll = mb - bb * SL;
        *(f32x4*)&base[((size_t)(bb * DI + nn)) * SL + ll] = a;
      } else {  // MEPI 2
#pragma unroll
        for (int r = 0; r < 4; ++r) {
          const size_t off = (size_t)(mb + r) * DM + n;
          const float nv = out[off] + a[r];
          out[off] = nv;
          outb[off] = cvt_bf(nv);
        }
      }
    }
  }
}

// ---------------- fp32 SIMT GEMM (dt_proj, K=24) ----------------
template <int EPI, bool KTAIL, int NCAP>
__global__ __launch_bounds__(256) void k_gemm(
    const float* __restrict__ A, const float* __restrict__ W,
    const float* __restrict__ bias, float* __restrict__ out, int K, int lda) {
  __shared__ float sm[4352];
  const int tid = threadIdx.x;
  const int m0 = blockIdx.x * 64;
  const int n0 = blockIdx.y * 64;
  const int b = m0 / SL, l0 = m0 % SL;
  const int tm = tid >> 4, tn = tid & 15;
  float acc[4][4] = {};
  float* As = sm;
  float* Ws = sm + 16 * 68;

  const int nk = (K + 15) / 16;
  for (int kt = 0; kt < nk; ++kt) {
    const int k0 = kt * 16;
    {
      const int row = tid >> 2;
      const int kq = (tid & 3) * 4;
      const int kb = k0 + kq;
      float4 v = make_float4(0.f, 0.f, 0.f, 0.f);
      if (!KTAIL || kb < K) v = *(const float4*)&A[(size_t)(m0 + row) * lda + kb];
      As[(kq + 0) * 68 + row] = v.x;
      As[(kq + 1) * 68 + row] = v.y;
      As[(kq + 2) * 68 + row] = v.z;
      As[(kq + 3) * 68 + row] = v.w;
    }
    {
      const int row = tid >> 2;
      const int kq = (tid & 3) * 4;
      const int kb = k0 + kq;
      float4 v = make_float4(0.f, 0.f, 0.f, 0.f);
      const bool nok = (NCAP % 64 == 0) || (n0 + row < NCAP);
      if (nok && (!KTAIL || kb < K)) v = *(const float4*)&W[(size_t)(n0 + row) * K + kb];
      Ws[(kq + 0) * 68 + row] = v.x;
      Ws[(kq + 1) * 68 + row] = v.y;
      Ws[(kq + 2) * 68 + row] = v.z;
      Ws[(kq + 3) * 68 + row] = v.w;
    }
    __syncthreads();
#pragma unroll
    for (int kk = 0; kk < 16; ++kk) {
      const float4 av = *(const float4*)&As[kk * 68 + 4 * tm];
      const float4 wv = *(const float4*)&Ws[kk * 68 + 4 * tn];
      const float ax[4] = {av.x, av.y, av.z, av.w};
      const float wx[4] = {wv.x, wv.y, wv.z, wv.w};
#pragma unroll
      for (int i = 0; i < 4; ++i)
#pragma unroll
        for (int j = 0; j < 4; ++j) acc[i][j] = fmaf(ax[i], wx[j], acc[i][j]);
    }
    __syncthreads();
  }

#pragma unroll
  for (int j = 0; j < 4; ++j) {
    const int nn = 4 * tn + j;
#pragma unroll
    for (int i = 0; i < 4; ++i) {
      float v = acc[i][j];
      if (EPI == 2) v = softplusf(v + bias[n0 + nn]);
      sm[nn * 68 + 4 * tm + i] = v;
    }
  }
  __syncthreads();
  const int row = tid >> 2;
  const int seg = (tid & 3) * 16;
  const float* src = &sm[row * 68 + seg];
  float* dst = out + ((size_t)(b * DI + n0 + row)) * SL + l0 + seg;
#pragma unroll
  for (int q = 0; q < 4; ++q) {
    *(float4*)&dst[q * 4] = *(const float4*)&src[q * 4];
  }
}

// ---------------- depthwise causal conv1d + bias + silu (4 l per thread) --------
__global__ void k_conv(const float* __restrict__ xcT, const float* __restrict__ cw,
                       const float* __restrict__ cb, float* __restrict__ uT) {
  const size_t idx = (size_t)blockIdx.x * 256 + threadIdx.x;
  const int l4 = (int)(idx % (SL / 4)) * 4;
  const int bd = (int)(idx / (SL / 4));
  const int d = bd % DI;
  const float* row = xcT + (size_t)bd * SL;
  const float4 w = *(const float4*)&cw[d * 4];
  const float4 cur = *(const float4*)&row[l4];
  float p1 = 0.f, p2 = 0.f, p3 = 0.f;
  if (l4 > 0) {
    const float4 pv = *(const float4*)&row[l4 - 4];
    p1 = pv.y; p2 = pv.z; p3 = pv.w;
  }
  const float cbd = cb[d];
  float4 o;
  o.x = cbd + w.w * cur.x + w.z * p3 + w.y * p2 + w.x * p1;
  o.y = cbd + w.w * cur.y + w.z * cur.x + w.y * p3 + w.x * p2;
  o.z = cbd + w.w * cur.z + w.z * cur.y + w.y * cur.x + w.x * p3;
  o.w = cbd + w.w * cur.w + w.z * cur.z + w.y * cur.y + w.x * cur.x;
  o.x = siluf(o.x); o.y = siluf(o.y); o.z = siluf(o.z); o.w = siluf(o.w);
  *(float4*)&uT[(size_t)bd * SL + l4] = o;
}

// ---------------- wave-synchronous fused selective scan -----------------------
// 1 wave per chain. lane = g*16+n. Tile = 64 steps. Stream-merging reduction:
// 4 rounds, active values halve; lane n ends holding y[l0+n]. 15 shuffles/tile.
__global__ __launch_bounds__(256) void k_scanw(
    const float* __restrict__ deltaT, const float* __restrict__ uT,
    const float* __restrict__ BC, const float* __restrict__ resT,
    const float* __restrict__ A_log, const float* __restrict__ Dp,
    float* __restrict__ yT) {
  const int tid = threadIdx.x;
  const int lane = tid & 63, wv = tid >> 6;
  const int n = lane & 15, g = lane >> 4;
  const int chain = blockIdx.x * 4 + wv;
  const int b = chain / DI, d = chain % DI;
  const float a2 = -expf(A_log[d * DSN + n]) * 1.44269504088896341f;
  const float dp = Dp[d];
  const float* drow = deltaT + (size_t)chain * SL;
  const float* urow = uT + (size_t)chain * SL;
  const float* resr = resT + (size_t)chain * SL;
  const float* bcb = BC + (size_t)b * SL * 32;
  float* yr = yT + (size_t)chain * SL;
  float carry = 0.f;
  const bool b0 = n & 1, b1 = (n >> 1) & 1, b2 = (n >> 2) & 1, b3 = (n >> 3) & 1;

  for (int tb = 0; tb < SL; tb += 64) {
    const int l0 = tb + g * 16;
    float da[16], dbu[16];
    float h = 0.f, dsum = 0.f;
#pragma unroll
    for (int k = 0; k < 16; ++k) {
      const float dl = drow[l0 + k];
      const float ul = urow[l0 + k];
      const float Bv = bcb[(size_t)(l0 + k) * 32 + n];
      const float e = exp2f(dl * a2);
      da[k] = e;
      dbu[k] = dl * ul * Bv;
      h = fmaf(e, h, dbu[k]);
      dsum += dl;
    }
    float Aagg = exp2f(a2 * dsum);
    float Bagg = h;
    // inclusive Hillis-Steele over the 4 groups (lane offsets 16, 32)
#pragma unroll
    for (int off = 16; off <= 32; off <<= 1) {
      const float Ae = __shfl(Aagg, (lane - off) & 63);
      const float Be = __shfl(Bagg, (lane - off) & 63);
      if (lane >= off) {
        Bagg = fmaf(Aagg, Be, Bagg);
        Aagg *= Ae;
      }
    }
    const float Pa = __shfl(Aagg, (lane - 16) & 63);
    const float Pb = __shfl(Bagg, (lane - 16) & 63);
    const float hstart = (g == 0) ? carry : fmaf(Pa, carry, Pb);
    const float cA = __shfl(Aagg, 48 | n);
    const float cB = __shfl(Bagg, 48 | n);
    // pass 2: cached-coefficient recurrence + C projection
    float p[16];
    h = hstart;
#pragma unroll
    for (int k = 0; k < 16; ++k) {
      h = fmaf(da[k], h, dbu[k]);
      p[k] = h * bcb[(size_t)(l0 + k) * 32 + 16 + n];
    }
    carry = fmaf(cA, carry, cB);
    // stream-merging reduction over the 16 state lanes:
    // round s: keep stream selected by bit s of n, send the other.
    float q8[8];
#pragma unroll
    for (int i = 0; i < 8; ++i) {
      const float mine = b0 ? p[2 * i + 1] : p[2 * i];
      const float oth = b0 ? p[2 * i] : p[2 * i + 1];
      q8[i] = mine + __shfl_xor(oth, 1);
    }
    float q4[4];
#pragma unroll
    for (int i = 0; i < 4; ++i) {
      const float mine = b1 ? q8[2 * i + 1] : q8[2 * i];
      const float oth = b1 ? q8[2 * i] : q8[2 * i + 1];
      q4[i] = mine + __shfl_xor(oth, 2);
    }
    float q2[2];
#pragma unroll
    for (int i = 0; i < 2; ++i) {
      const float mine = b2 ? q4[2 * i + 1] : q4[2 * i];
      const float oth = b2 ? q4[2 * i] : q4[2 * i + 1];
      q2[i] = mine + __shfl_xor(oth, 4);
    }
    const float mine = b3 ? q2[1] : q2[0];
    const float oth = b3 ? q2[0] : q2[1];
    const float ysum = mine + __shfl_xor(oth, 8);
    // lane n now holds y for step l0+n
    const float ul = urow[l0 + n];
    const float r = resr[l0 + n];
    yr[l0 + n] = (ysum + ul * dp) * siluf(r);
  }
}

// ---------------- RMS denom ----------------
__global__ void k_rinv(const float* __restrict__ t, float* __restrict__ rinv) {
  const int row = blockIdx.x;
  const float* tr = t + (size_t)row * DM;
  const int tid = threadIdx.x;
  float ss = 0.f;
#pragma unroll
  for (int k = 0; k < DM / 64; ++k) {
    const float v = tr[tid + k * 64];
    ss = fmaf(v, v, ss);
  }
  ss += __shfl_xor(ss, 1);
  ss += __shfl_xor(ss, 2);
  ss += __shfl_xor(ss, 4);
  ss += __shfl_xor(ss, 8);
  ss += __shfl_xor(ss, 16);
  ss += __shfl_xor(ss, 32);
  if (tid == 0) rinv[row] = 1.f / sqrtf(ss / DM + 1e-5f);
}

// ---------------- pooled partial sums ----------------
__global__ void k_pool(const float* __restrict__ t, const float* __restrict__ rinv,
                       float* __restrict__ part) {
  const int b = blockIdx.x, dmb = blockIdx.y, ch = blockIdx.z;
  const int dm = dmb * 64 + threadIdx.x;
  const int lbeg = ch * (SL / 32);
  float s = 0.f;
  for (int l = lbeg; l < lbeg + SL / 32; ++l)
    s = fmaf(t[((size_t)b * SL + l) * DM + dm], rinv[b * SL + l], s);
  part[((size_t)ch * NB + b) * DM + dm] = s;
}

// ---------------- head ----------------
__global__ void k_head(const float* __restrict__ part, const float* __restrict__ norm_w,
                       const float* __restrict__ hw, const float* __restrict__ hb,
                       float* __restrict__ out) {
  const int b = blockIdx.x;
  const int tid = threadIdx.x;
  __shared__ float pv[DM];
  for (int k = tid; k < DM; k += 64) {
    float s = 0.f;
#pragma unroll
    for (int c = 0; c < 32; ++c) s += part[((size_t)c * NB + b) * DM + k];
    pv[k] = s * norm_w[k] * (1.f / SL);
  }
  __syncthreads();
  const int cls = blockIdx.y * 64 + tid;
  if (cls < NCLS) {
    const float* wr = hw + (size_t)cls * DM;
    float acc = hb[cls];
#pragma unroll 4
    for (int k = 0; k < DM; k += 4) {
      const float4 w4 = *(const float4*)&wr[k];
      acc = fmaf(pv[k], w4.x, acc);
      acc = fmaf(pv[k + 1], w4.y, acc);
      acc = fmaf(pv[k + 2], w4.z, acc);
      acc = fmaf(pv[k + 3], w4.w, acc);
    }
    out[(size_t)b * NCLS + cls] = acc;
  }
}

extern "C" void kernel_launch(void* const* d_in, const int* in_sizes, int n_in,
                              void* d_out, int out_size, void* d_ws, size_t ws_size,
                              hipStream_t stream) {
  (void)in_sizes; (void)n_in; (void)out_size; (void)ws_size;
  const float* x = (const float*)d_in[0];
  const float* patch_w = (const float*)d_in[1];
  const float* patch_b = (const float*)d_in[2];
  const float* in_proj_w = (const float*)d_in[3];
  const float* conv_w = (const float*)d_in[4];
  const float* conv_b = (const float*)d_in[5];
  const float* x_proj_w = (const float*)d_in[6];
  const float* dt_proj_w = (const float*)d_in[7];
  const float* dt_proj_b = (const float*)d_in[8];
  const float* A_log = (const float*)d_in[9];
  const float* Dp = (const float*)d_in[10];
  const float* out_proj_w = (const float*)d_in[11];
  const float* norm_w = (const float*)d_in[12];
  const float* head_w = (const float*)d_in[13];
  const float* head_b = (const float*)d_in[14];

  float* ws = (float*)d_ws;
  size_t o = 0;
  float* t = ws + o;     o += (size_t)NB * SL * DM;
  float* xcT = ws + o;   o += (size_t)NB * DI * SL;
  float* resT = ws + o;  o += (size_t)NB * DI * SL;
  float* uT = ws + o;    o += (size_t)NB * DI * SL;
  float* dltT = ws + o;  o += (size_t)NB * DI * SL;
  float* yT = ws + o;    o += (size_t)NB * DI * SL;
  float* dbl24 = ws + o; o += (size_t)NB * SL * DR;
  float* BC = ws + o;    o += (size_t)NB * SL * 32;
  float* rinv = ws + o;  o += (size_t)NB * SL;
  float* part = ws + o;  o += (size_t)32 * NB * DM;
  unsigned short* tb = (unsigned short*)(ws + o); o += (size_t)NB * SL * DM / 2;

  k_patch<<<NB * SL, 128, 0, stream>>>(x, patch_w, patch_b, t, tb);

  for (int i = 0; i < NLAYER; ++i) {
    // in_proj: tb[M,384](bf16) x W[1536,384]^T -> xcT / resT ([b][n][l] fp32)
    k_mgemm<128, 128, 1, 1536, false><<<dim3(98, 12), 256, 0, stream>>>(
        tb, nullptr, in_proj_w + (size_t)i * 2 * DI * DM, xcT, resT, nullptr, DM);
    // depthwise causal conv + silu -> uT
    k_conv<<<(NB * DI * SL / 4) / 256, 256, 0, stream>>>(
        xcT, conv_w + (size_t)i * DI * 4, conv_b + (size_t)i * DI, uT);
    // x_proj: uT (AT-staged bf16) x W[56,768]^T -> dbl24 + BC[b][l][32]
    k_mgemm<64, 64, 0, XPN, true><<<dim3(196, 1), 256, 0, stream>>>(
        nullptr, uT, x_proj_w + (size_t)i * XPN * DI, dbl24, BC, nullptr, DI);
    // dt_proj (fp32 SIMT): softplus(dbl24 @ dt_w^T + b) -> dltT [b][d][l]
    k_gemm<2, true, 64><<<dim3(196, 12), 256, 0, stream>>>(
        dbl24, dt_proj_w + (size_t)i * DI * DR, dt_proj_b + (size_t)i * DI, dltT,
        DR, DR);
    // wave-synchronous fused selective scan + gate -> yT
    k_scanw<<<NCHAIN / 4, 256, 0, stream>>>(
        dltT, uT, BC, resT, A_log + (size_t)i * DI * DSN, Dp + (size_t)i * DI, yT);
    // out_proj: yT (AT-staged bf16) x W[384,768]^T -> t += ; tb = bf16(t)
    k_mgemm<128, 128, 2, 384, true><<<dim3(98, 3), 256, 0, stream>>>(
        nullptr, yT, out_proj_w + (size_t)i * DM * DI, t, nullptr, tb, DI);
  }

  k_rinv<<<NB * SL, 64, 0, stream>>>(t, rinv);
  k_pool<<<dim3(NB, DM / 64, 32), 64, 0, stream>>>(t, rinv, part);
  k_head<<<dim3(NB, 16), 64, 0, stream>>>(part, norm_w, head_w, head_b, (float*)d_out);
}